// Round 17
// baseline (158.714 us; speedup 1.0000x reference)
//
#include <hip/hip_runtime.h>

// ---------------------------------------------------------------------------
// TPA attention, factorized to GQA flash attention.
// B=1, S=2048, HID=2048, H=16, KVH=8, D=128, QR=6, KR=2, VR=2
// ---------------------------------------------------------------------------

constexpr int SEQ   = 2048;
constexpr int HIDN  = 2048;
constexpr int NHEAD = 16;
constexpr int NKVH  = 8;
constexpr int DH    = 128;
constexpr int NCOLS = 1408;   // 96 Aq | 16 Ak | 16 Av | 768 Bq | 256 Bk | 256 Bv

typedef __bf16 bf16x8 __attribute__((ext_vector_type(8)));
typedef float  f32x4  __attribute__((ext_vector_type(4)));

#define MFMA(a, b, c) __builtin_amdgcn_mfma_f32_16x16x32_bf16((a), (b), (c), 0, 0, 0)

__device__ __forceinline__ void gload_lds16(const void* g, void* l) {
  __builtin_amdgcn_global_load_lds(
      (const __attribute__((address_space(1))) void*)g,
      (__attribute__((address_space(3))) void*)l, 16, 0, 0);
}

// ---- prep: hidden cvt + W_all^T transpose (WoT lives in proj launch) ------

__global__ __launch_bounds__(256) void k_prep(
    const float* __restrict__ hidden,
    const float* __restrict__ WAq, const float* __restrict__ WAk,
    const float* __restrict__ WAv, const float* __restrict__ WBq,
    const float* __restrict__ WBk, const float* __restrict__ WBv,
    __bf16* __restrict__ hid_bf, __bf16* __restrict__ WT) {
  const int bid = blockIdx.x;
  if (bid < 2048) {                       // ---- hidden f32 -> bf16, x8
    const int i = (bid * 256 + threadIdx.x) * 8;
    f32x4 a = *(const f32x4*)(hidden + i);
    f32x4 b = *(const f32x4*)(hidden + i + 4);
    bf16x8 v;
#pragma unroll
    for (int j = 0; j < 4; j++) { v[j] = (__bf16)a[j]; v[4 + j] = (__bf16)b[j]; }
    *(bf16x8*)(hid_bf + i) = v;
  } else {                                // ---- W_all^T [1408][2048]
    const int t = bid - 2048;             // t < 44*64
    const int bc = (t % 44) * 32, bk = (t / 44) * 32;
    __shared__ float tl[32][33];
    const int tx = threadIdx.x & 31, ty = threadIdx.x >> 5;  // ty 0..7
    const int c = bc + tx;
#pragma unroll
    for (int j = 0; j < 32; j += 8) {
      const int k = bk + ty + j;
      float v;
      if (c < 96)        v = WAq[k * 96 + c];
      else if (c < 112)  v = WAk[k * 16 + (c - 96)];
      else if (c < 128)  v = WAv[k * 16 + (c - 112)];
      else if (c < 896)  v = WBq[k * 768 + (c - 128)];
      else if (c < 1152) v = WBk[k * 256 + (c - 896)];
      else               v = WBv[k * 256 + (c - 1152)];
      tl[ty + j][tx] = v;                 // tl[k-local][c-local]
    }
    __syncthreads();
#pragma unroll
    for (int j = 0; j < 32; j += 8)
      WT[(size_t)(bc + ty + j) * HIDN + bk + tx] = (__bf16)tl[tx][ty + j];
  }
}

// ---- fused: proj GEMM split-K=2 (704 blocks) + Wo^T transpose (4096) ------

__global__ __launch_bounds__(256) void k_proj_wo(
    const __bf16* __restrict__ A, const __bf16* __restrict__ BT,
    float* __restrict__ C0, float* __restrict__ C1,
    const float* __restrict__ Wo, __bf16* __restrict__ WoT) {
  __shared__ char smem[49152];            // GEMM: As 32KB | Bs 16KB ; WoT: 4.2KB
  const int bid = blockIdx.x;
  if (bid >= 704) {                       // ---- Wo^T [2048][2048] tile
    const int t = bid - 704;
    const int bn = (t % 64) * 32, bk = (t / 64) * 32;
    float (*tl)[33] = (float(*)[33])smem;
    const int tx = threadIdx.x & 31, ty = threadIdx.x >> 5;
#pragma unroll
    for (int j = 0; j < 32; j += 8)
      tl[ty + j][tx] = Wo[(size_t)(bk + ty + j) * HIDN + bn + tx];
    __syncthreads();
#pragma unroll
    for (int j = 0; j < 32; j += 8)
      WoT[(size_t)(bn + ty + j) * HIDN + bk + tx] = (__bf16)tl[tx][ty + j];
    return;
  }
  // ---- proj GEMM: C[2048][1408] = A[2048][2048] * BT[1408][2048]^T
  const int K = HIDN, N = NCOLS;
  __bf16* As = (__bf16*)smem;             // [4][4096]
  __bf16* Bs = (__bf16*)(smem + 32768);   // [4][2048]
  const int tid = threadIdx.x;
  const int w = tid >> 6, lane = tid & 63;
  const int lhi = lane >> 4, llo = lane & 15;
  const int wr = w >> 1, wc = w & 1;
  const int z = (bid >= 352);
  const int b = bid - z * 352;
  float* C = z ? C1 : C0;
  const int kbase = z * (K >> 1);
  const int sid = (b & 7) * 44 + (b >> 3);   // chunk swizzle (352 % 8 == 0)
  const int brow = (sid / 22) * 128, bcol = (sid % 22) * 64;
  const int rA = lane >> 2, kA = (lane & 3) * 8;
  const int nt = K >> 6;                  // 32 K-steps per half

  f32x4 acc[4][2];
#pragma unroll
  for (int m = 0; m < 4; m++)
#pragma unroll
    for (int n = 0; n < 2; n++) acc[m][n] = (f32x4){0.f, 0.f, 0.f, 0.f};

  auto stage = [&](int t) {               // 3 gload_lds per wave
    const int buf = t & 3;
    const int k0 = kbase + t * 32;
#pragma unroll
    for (int i = 0; i < 2; i++) {
      int seg = w * 2 + i;
      int row = seg * 16 + rA;
      gload_lds16(A + (size_t)(brow + row) * K + k0 + kA,
                  As + buf * 4096 + seg * 512);
    }
    gload_lds16(BT + (size_t)(bcol + w * 16 + rA) * K + k0 + kA,
                Bs + buf * 2048 + w * 512);
  };

  stage(0); stage(1); stage(2);
  asm volatile("s_waitcnt vmcnt(6)" ::: "memory");
  __builtin_amdgcn_s_barrier();

  for (int t = 0; t < nt; t++) {
    if (t + 3 < nt) stage(t + 3);
    const int buf = t & 3;
    bf16x8 af[4], bfr[2];
#pragma unroll
    for (int m = 0; m < 4; m++)
      af[m] = *(const bf16x8*)&As[buf * 4096 + (wr * 64 + m * 16 + llo) * 32 + lhi * 8];
#pragma unroll
    for (int n = 0; n < 2; n++)
      bfr[n] = *(const bf16x8*)&Bs[buf * 2048 + (wc * 32 + n * 16 + llo) * 32 + lhi * 8];
#pragma unroll
    for (int m = 0; m < 4; m++)
#pragma unroll
      for (int n = 0; n < 2; n++) acc[m][n] = MFMA(af[m], bfr[n], acc[m][n]);
    const int rem = nt - 2 - t;
    if (rem >= 2)      asm volatile("s_waitcnt vmcnt(6)" ::: "memory");
    else if (rem == 1) asm volatile("s_waitcnt vmcnt(3)" ::: "memory");
    else               asm volatile("s_waitcnt vmcnt(0)" ::: "memory");
    __builtin_amdgcn_s_barrier();
  }

#pragma unroll
  for (int m = 0; m < 4; m++)
#pragma unroll
    for (int n = 0; n < 2; n++) {
      int r0 = brow + wr * 64 + m * 16 + lhi * 4;
      int c0 = bcol + wc * 32 + n * 16 + llo;
#pragma unroll
      for (int r = 0; r < 4; r++) C[(size_t)(r0 + r) * N + c0] = acc[m][n][r];
    }
}

// ---- out GEMM: 128x128 tile, 8 waves (2x4), 512 threads, 4-deep pipeline --

__global__ __launch_bounds__(512) void k_gemm_out(const __bf16* __restrict__ A,
                                                  const __bf16* __restrict__ BT,
                                                  float* __restrict__ C) {
  __shared__ __bf16 As[4][4096];  // [buf][128 rows][32 k]
  __shared__ __bf16 Bs[4][4096];  // [buf][128 cols][32 k]
  const int K = HIDN, N = HIDN;
  const int tid = threadIdx.x;
  const int w = tid >> 6, lane = tid & 63;
  const int lhi = lane >> 4, llo = lane & 15;
  const int wr = w >> 2, wc = w & 3;

  // 2D region per XCD: 8 rows x 4 cols of 128x128 tiles
  const int id = blockIdx.y * 16 + blockIdx.x;
  const int g = id & 7, kk = id >> 3;     // kk 0..31
  const int rg = g >> 2, cg = g & 3;
  const int brow = (rg * 8 + (kk & 7)) * 128;
  const int bcol = (cg * 4 + (kk >> 3)) * 128;

  const int rA = tid >> 2, kA = (tid & 3) * 8;  // thread -> (row, k-chunk)
  const int nt = K >> 5;                        // 64

  f32x4 acc[4][2];
#pragma unroll
  for (int m = 0; m < 4; m++)
#pragma unroll
    for (int n = 0; n < 2; n++) acc[m][n] = (f32x4){0.f, 0.f, 0.f, 0.f};

  auto stage = [&](int t) {               // 2 gload_lds per wave
    const int buf = t & 3;
    const int k0 = t * 32;
    gload_lds16(A  + (size_t)(brow + rA) * K + k0 + kA, &As[buf][w * 512]);
    gload_lds16(BT + (size_t)(bcol + rA) * K + k0 + kA, &Bs[buf][w * 512]);
  };

  stage(0); stage(1); stage(2);
  asm volatile("s_waitcnt vmcnt(4)" ::: "memory");   // tile 0 landed
  __builtin_amdgcn_s_barrier();

  for (int t = 0; t < nt; t++) {
    if (t + 3 < nt) stage(t + 3);
    const int buf = t & 3;
    bf16x8 af[4], bfr[2];
#pragma unroll
    for (int m = 0; m < 4; m++)
      af[m] = *(const bf16x8*)&As[buf][(wr * 64 + m * 16 + llo) * 32 + lhi * 8];
#pragma unroll
    for (int n = 0; n < 2; n++)
      bfr[n] = *(const bf16x8*)&Bs[buf][(wc * 32 + n * 16 + llo) * 32 + lhi * 8];
#pragma unroll
    for (int m = 0; m < 4; m++)
#pragma unroll
      for (int n = 0; n < 2; n++) acc[m][n] = MFMA(af[m], bfr[n], acc[m][n]);
    const int rem = nt - 2 - t;
    if (rem >= 2)      asm volatile("s_waitcnt vmcnt(4)" ::: "memory");
    else if (rem == 1) asm volatile("s_waitcnt vmcnt(2)" ::: "memory");
    else               asm volatile("s_waitcnt vmcnt(0)" ::: "memory");
    __builtin_amdgcn_s_barrier();
  }

#pragma unroll
  for (int m = 0; m < 4; m++)
#pragma unroll
    for (int n = 0; n < 2; n++) {
      int r0 = brow + wr * 64 + m * 16 + lhi * 4;
      int c0 = bcol + wc * 32 + n * 16 + llo;
#pragma unroll
      for (int r = 0; r < 4; r++) C[(size_t)(r0 + r) * N + c0] = acc[m][n][r];
    }
}

// ---- build Q/K/Vp from projection PARTIALS (sum + rope + rank contraction)

__global__ __launch_bounds__(128) void k_build_qkv(const float* __restrict__ P0,
                                                   const float* __restrict__ P1,
                                                   const float* __restrict__ cosT,
                                                   const float* __restrict__ sinT,
                                                   __bf16* __restrict__ Qo,
                                                   __bf16* __restrict__ Ko,
                                                   __bf16* __restrict__ Vto) {
  const int q = blockIdx.x, d = threadIdx.x;  // 128 threads
  __shared__ float Ash[128];                  // Aq(96) | Ak(16) | Av(16)
  const float* r0 = P0 + (size_t)q * NCOLS;
  const float* r1 = P1 + (size_t)q * NCOLS;
  auto rd = [&](int i) { return r0[i] + r1[i]; };  // merge split-K halves
  Ash[d] = rd(d);
  __syncthreads();
  const int m2 = (d >> 1) * 2;
  const bool odd = d & 1;
  const float c = cosT[q * 64 + (d >> 1)];
  const float s = sinT[q * 64 + (d >> 1)];

  float qacc[16];
#pragma unroll
  for (int h = 0; h < 16; h++) qacc[h] = 0.f;
#pragma unroll
  for (int r = 0; r < 6; r++) {
    float xe = rd(128 + r * 128 + m2);
    float xo = rd(128 + r * 128 + m2 + 1);
    float br = odd ? (xe * s + xo * c) : (xe * c - xo * s);
#pragma unroll
    for (int h = 0; h < 16; h++) qacc[h] += Ash[h * 6 + r] * br;
  }
#pragma unroll
  for (int h = 0; h < 16; h++)
    Qo[((size_t)h * SEQ + q) * DH + d] = (__bf16)(qacc[h] * 0.08838834764831845f);

  float kacc[8];
#pragma unroll
  for (int g = 0; g < 8; g++) kacc[g] = 0.f;
#pragma unroll
  for (int ss = 0; ss < 2; ss++) {
    float xe = rd(896 + ss * 128 + m2);
    float xo = rd(896 + ss * 128 + m2 + 1);
    float bs = odd ? (xe * s + xo * c) : (xe * c - xo * s);
#pragma unroll
    for (int g = 0; g < 8; g++) kacc[g] += Ash[96 + g * 2 + ss] * bs;
  }
#pragma unroll
  for (int g = 0; g < 8; g++)
    Ko[((size_t)g * SEQ + q) * DH + d] = (__bf16)kacc[g];

  float vacc[8];
#pragma unroll
  for (int g = 0; g < 8; g++) vacc[g] = 0.f;
#pragma unroll
  for (int u = 0; u < 2; u++) {
    float vu = rd(1152 + u * 128 + d);
#pragma unroll
    for (int g = 0; g < 8; g++) vacc[g] += Ash[112 + g * 2 + u] * vu;
  }
  // pi(k) = ((k&15)>>2)*8 + (k&3) + ((k&16)>>2)
  const int qp = (q & ~31) | (((q & 15) >> 2) * 8 + (q & 3) + ((q & 16) >> 2));
#pragma unroll
  for (int g = 0; g < 8; g++)
    Vto[((size_t)g * DH + d) * SEQ + qp] = (__bf16)vacc[g];
}

// ---- flash attention: 4-buffer, ONE barrier per tile ----------------------
// split-KV parts=2, XCD-affine, swapped QK^T + in-register P, key-permuted V.
// NEW vs R15: staging uses 4 LDS buffers (64KB) + depth-2 prefetch so the
// end-of-loop WAR barrier is DELETED — stage(t+2) overwrites the buffer last
// read by compute(t-2), and every wave passed top-barrier(t-1) after
// finishing compute(t-2) => race-free with one barrier/tile (same proof and
// pattern as k_gemm_bt, bit-exact since R8). Occupancy is workload-limited
// (~8 waves/CU at any LDS 32-49KB, R12-R16), so 64KB costs nothing.

__global__ __launch_bounds__(256) void k_attn(const __bf16* __restrict__ Q,
                                              const __bf16* __restrict__ Kc,
                                              const __bf16* __restrict__ Vt,
                                              float* __restrict__ AOf0,
                                              float* __restrict__ AOf1,
                                              float* __restrict__ Ls) {
  const int raw = blockIdx.x;          // 0..1023
  const int g = raw & 7;               // XCD affinity
  const int j = raw >> 3;              // 0..127
  const int bqi = 31 - (j >> 2);       // heavy-first per XCD stripe
  const int hh = (j >> 1) & 1;
  const int p = j & 1;
  const int h = g * 2 + hh;
  const int w = threadIdx.x >> 6, lane = threadIdx.x & 63;
  const int lhi = lane >> 4, llo = lane & 15;
  const int q0 = bqi * 64 + w * 16;
  const int t0 = p * (bqi + 1), t1 = t0 + bqi + 1;  // half the causal tiles

  __shared__ __bf16 KVs[4][8192];    // 4 bufs x (8KB K swz | 8KB V perm)

  const __bf16* Qh = Q  + (size_t)h * SEQ * DH;
  const __bf16* Kg = Kc + (size_t)g * SEQ * DH;
  const __bf16* Vg = Vt + (size_t)g * DH * SEQ;
  float* AOc = p ? AOf1 : AOf0;

  bf16x8 aq[4];
#pragma unroll
  for (int c = 0; c < 4; c++)
    aq[c] = *(const bf16x8*)&Qh[(size_t)(q0 + llo) * DH + c * 32 + lhi * 8];

  f32x4 oacc[8];
  float lsum = 0.f;
#pragma unroll
  for (int n = 0; n < 8; n++) oacc[n] = (f32x4){0.f, 0.f, 0.f, 0.f};

  // PV B-frag read: one b128 at kslots lhi*8..+7, row d = n*16+llo.
  const int vb = llo * 64 + ((lhi ^ ((llo >> 1) & 3)) << 4);

  auto stage = [&](int kb, int buf) {   // 4 gload_lds per wave
    __bf16* L = KVs[buf];
    if (w < 2) {
#pragma unroll
      for (int u = 0; u < 4; u++) {
        int c = w * 256 + u * 64 + lane;
        int row = c >> 4, jj = c & 15;
        gload_lds16(Kg + (size_t)(kb + row) * DH + ((jj ^ (row & 7)) * 8),
                    L + (w * 256 + u * 64) * 8);
      }
    } else {
#pragma unroll
      for (int u = 0; u < 4; u++) {
        int c = (w - 2) * 256 + u * 64 + lane;
        int d = c >> 2, jj = c & 3;
        gload_lds16(Vg + (size_t)d * SEQ + kb + ((jj ^ ((d >> 1) & 3)) * 8),
                    L + 4096 + ((w - 2) * 256 + u * 64) * 8);
      }
    }
  };

  stage(t0 * 32, t0 & 3);
  if (t0 + 1 < t1) stage((t0 + 1) * 32, (t0 + 1) & 3);
  for (int t = t0; t < t1; t++) {
    const int kb = t * 32;
    const int buf = t & 3;
    if (t + 2 < t1) {
      stage((t + 2) * 32, (t + 2) & 3);
      asm volatile("s_waitcnt vmcnt(8)" ::: "memory");  // tile t landed
    } else if (t + 1 < t1) {
      asm volatile("s_waitcnt vmcnt(4)" ::: "memory");
    } else {
      asm volatile("s_waitcnt vmcnt(0)" ::: "memory");
    }
    __builtin_amdgcn_s_barrier();        // the ONLY barrier per tile
    if (kb <= q0 + 15) {   // wave-uniform skip of fully-masked tiles
      const char* Kl = (const char*)KVs[buf];
      const char* Vl = (const char*)(KVs[buf] + 4096);
      f32x4 s0 = {0.f, 0.f, 0.f, 0.f}, s1 = {0.f, 0.f, 0.f, 0.f};
#pragma unroll
      for (int c = 0; c < 4; c++) {
        const int row0 = llo, row1 = 16 + llo;
        bf16x8 k0 = *(const bf16x8*)(Kl + row0 * 256 +
                                     ((c * 64 + lhi * 16) ^ ((row0 & 7) << 4)));
        bf16x8 k1 = *(const bf16x8*)(Kl + row1 * 256 +
                                     ((c * 64 + lhi * 16) ^ ((row1 & 7) << 4)));
        s0 = MFMA(k0, aq[c], s0);   // swapped: S^T[key][q]
        s1 = MFMA(k1, aq[c], s1);
      }
      float e[8];
#pragma unroll
      for (int r = 0; r < 4; r++) {
        float a0 = exp2f(s0[r] * 0.057707802f);
        float a1 = exp2f(s1[r] * 0.057707802f);
        e[r]     = exp2f(72.134752f - 144.269504f * __builtin_amdgcn_rcpf(a0 + 1.f));
        e[4 + r] = exp2f(72.134752f - 144.269504f * __builtin_amdgcn_rcpf(a1 + 1.f));
      }
      if (kb + 31 > q0) {          // diagonal tile only: causal mask
        const int qrow = q0 + llo;
#pragma unroll
        for (int r = 0; r < 4; r++) {
          if (kb + lhi * 4 + r > qrow)      e[r] = 0.f;
          if (kb + 16 + lhi * 4 + r > qrow) e[4 + r] = 0.f;
        }
      }
#pragma unroll
      for (int r = 0; r < 4; r++) lsum += e[r] + e[4 + r];
      union { bf16x8 v8; unsigned u[4]; } pu;
      asm("v_cvt_pk_bf16_f32 %0, %1, %2" : "=v"(pu.u[0]) : "v"(e[0]), "v"(e[1]));
      asm("v_cvt_pk_bf16_f32 %0, %1, %2" : "=v"(pu.u[1]) : "v"(e[2]), "v"(e[3]));
      asm("v_cvt_pk_bf16_f32 %0, %1, %2" : "=v"(pu.u[2]) : "v"(e[4]), "v"(e[5]));
      asm("v_cvt_pk_bf16_f32 %0, %1, %2" : "=v"(pu.u[3]) : "v"(e[6]), "v"(e[7]));
#pragma unroll
      for (int n = 0; n < 8; n++) {
        bf16x8 vf = *(const bf16x8*)(Vl + vb + n * 1024);
        oacc[n] = MFMA(pu.v8, vf, oacc[n]);
      }
    }
  }

  float tsum = lsum;
  tsum += __shfl_xor(tsum, 16);
  tsum += __shfl_xor(tsum, 32);
  if (lhi == 0) Ls[((size_t)p * NHEAD + h) * SEQ + q0 + llo] = tsum;
#pragma unroll
  for (int r = 0; r < 4; r++) {
    const int qrow = q0 + lhi * 4 + r;
#pragma unroll
    for (int n = 0; n < 8; n++)
      AOc[(size_t)qrow * HIDN + h * DH + n * 16 + llo] = oacc[n][r];
  }
}

// ---- merge split-KV partials, normalize, cast to bf16 ---------------------

__global__ __launch_bounds__(256) void k_norm(const float* __restrict__ A0,
                                              const float* __restrict__ A1,
                                              const float* __restrict__ Ls,
                                              __bf16* __restrict__ AO) {
  const int i = (blockIdx.x * 256 + threadIdx.x) * 4;  // 4M elems, f32x4
  const int q = i >> 11, h = (i & 2047) >> 7;
  const float inv = 1.f / (Ls[h * SEQ + q] + Ls[(NHEAD + h) * SEQ + q]);
  f32x4 a = *(const f32x4*)(A0 + i);
  f32x4 b = *(const f32x4*)(A1 + i);
#pragma unroll
  for (int j = 0; j < 4; j++) AO[i + j] = (__bf16)((a[j] + b[j]) * inv);
}

// ---------------------------------------------------------------------------

extern "C" void kernel_launch(void* const* d_in, const int* in_sizes, int n_in,
                              void* d_out, int out_size, void* d_ws, size_t ws_size,
                              hipStream_t stream) {
  const float* hidden = (const float*)d_in[0];
  const float* cosT   = (const float*)d_in[1];
  const float* sinT   = (const float*)d_in[2];
  // d_in[3] = mask (pure causal, computed analytically), d_in[4] = arange (unused)
  const float* WAq = (const float*)d_in[5];
  const float* WAk = (const float*)d_in[6];
  const float* WAv = (const float*)d_in[7];
  const float* WBq = (const float*)d_in[8];
  const float* WBk = (const float*)d_in[9];
  const float* WBv = (const float*)d_in[10];
  const float* Wo  = (const float*)d_in[11];
  float* out = (float*)d_out;

  // Workspace layout (lifetime-aliased), ~67.9 MB:
  //   [0)          hid_bf (8.39M)  -> AOf0 (16.78M) after proj is done
  //   [8388608)    WallT  (5.77M)      (overlaid by AOf0)
  //   [14155776)   Pp0    (11.53M)     (first 2.6M overlaid by AOf0; dead
  //                                     after build_qkv)
  //   [25690112)   WoT    (8.39M)      (live until final GEMM)
  //   [34078720)   Qb     (8.39M)  -> AO bf16 after attn is done
  //   [42467328)   Kb     (4.19M)
  //   [46661632)   Vt     (4.19M)
  //   [50855936)   Pp1    (11.53M) -> AOf1 (16.78M) after build_qkv is done
  //   [67633152)   Ls     (0.26M)
  char* ws = (char*)d_ws;
  __bf16* hid_bf = (__bf16*)(ws);
  __bf16* WallT  = (__bf16*)(ws + 8388608);
  float*  Pp0    = (float*)(ws + 14155776);
  __bf16* WoT    = (__bf16*)(ws + 25690112);
  __bf16* Qb     = (__bf16*)(ws + 34078720);
  __bf16* Kb     = (__bf16*)(ws + 42467328);
  __bf16* Vt     = (__bf16*)(ws + 46661632);
  float*  Pp1    = (float*)(ws + 50855936);
  float*  AOf0   = (float*)(ws);
  float*  AOf1   = (float*)(ws + 50855936);
  float*  Ls     = (float*)(ws + 67633152);
  __bf16* AO     = (__bf16*)(ws + 34078720);  // aliases Qb (dead after attn)

  // prep: 2048 cvt blocks + 44*64 wall-transpose
  k_prep<<<2048 + 44 * 64, 256, 0, stream>>>(
      hidden, WAq, WAk, WAv, WBq, WBk, WBv, hid_bf, WallT);
  // proj GEMM split-K=2 (704 blocks) + WoT transpose (4096 blocks) fused
  k_proj_wo<<<704 + 4096, 256, 0, stream>>>(hid_bf, WallT, Pp0, Pp1, Wo, WoT);
  k_build_qkv<<<SEQ, 128, 0, stream>>>(Pp0, Pp1, cosT, sinT, Qb, Kb, Vt);
  k_attn<<<1024, 256, 0, stream>>>(Qb, Kb, Vt, AOf0, AOf1, Ls);
  k_norm<<<(SEQ * HIDN / 4) / 256, 256, 0, stream>>>(AOf0, AOf1, Ls, AO);
  k_gemm_out<<<dim3(16, 16), 512, 0, stream>>>(AO, WoT, out);
}

// Round 18
// 151.292 us; speedup vs baseline: 1.0491x; 1.0491x over previous
//
#include <hip/hip_runtime.h>

// ---------------------------------------------------------------------------
// TPA attention, factorized to GQA flash attention.
// B=1, S=2048, HID=2048, H=16, KVH=8, D=128, QR=6, KR=2, VR=2
// ---------------------------------------------------------------------------

constexpr int SEQ   = 2048;
constexpr int HIDN  = 2048;
constexpr int NHEAD = 16;
constexpr int NKVH  = 8;
constexpr int DH    = 128;
constexpr int NCOLS = 1408;   // 96 Aq | 16 Ak | 16 Av | 768 Bq | 256 Bk | 256 Bv

typedef __bf16 bf16x8 __attribute__((ext_vector_type(8)));
typedef float  f32x4  __attribute__((ext_vector_type(4)));

#define MFMA(a, b, c) __builtin_amdgcn_mfma_f32_16x16x32_bf16((a), (b), (c), 0, 0, 0)

__device__ __forceinline__ void gload_lds16(const void* g, void* l) {
  __builtin_amdgcn_global_load_lds(
      (const __attribute__((address_space(1))) void*)g,
      (__attribute__((address_space(3))) void*)l, 16, 0, 0);
}

// ---- prep: hidden cvt + W_all^T transpose (WoT lives in proj launch) ------

__global__ __launch_bounds__(256) void k_prep(
    const float* __restrict__ hidden,
    const float* __restrict__ WAq, const float* __restrict__ WAk,
    const float* __restrict__ WAv, const float* __restrict__ WBq,
    const float* __restrict__ WBk, const float* __restrict__ WBv,
    __bf16* __restrict__ hid_bf, __bf16* __restrict__ WT) {
  const int bid = blockIdx.x;
  if (bid < 2048) {                       // ---- hidden f32 -> bf16, x8
    const int i = (bid * 256 + threadIdx.x) * 8;
    f32x4 a = *(const f32x4*)(hidden + i);
    f32x4 b = *(const f32x4*)(hidden + i + 4);
    bf16x8 v;
#pragma unroll
    for (int j = 0; j < 4; j++) { v[j] = (__bf16)a[j]; v[4 + j] = (__bf16)b[j]; }
    *(bf16x8*)(hid_bf + i) = v;
  } else {                                // ---- W_all^T [1408][2048]
    const int t = bid - 2048;             // t < 44*64
    const int bc = (t % 44) * 32, bk = (t / 44) * 32;
    __shared__ float tl[32][33];
    const int tx = threadIdx.x & 31, ty = threadIdx.x >> 5;  // ty 0..7
    const int c = bc + tx;
#pragma unroll
    for (int j = 0; j < 32; j += 8) {
      const int k = bk + ty + j;
      float v;
      if (c < 96)        v = WAq[k * 96 + c];
      else if (c < 112)  v = WAk[k * 16 + (c - 96)];
      else if (c < 128)  v = WAv[k * 16 + (c - 112)];
      else if (c < 896)  v = WBq[k * 768 + (c - 128)];
      else if (c < 1152) v = WBk[k * 256 + (c - 896)];
      else               v = WBv[k * 256 + (c - 1152)];
      tl[ty + j][tx] = v;                 // tl[k-local][c-local]
    }
    __syncthreads();
#pragma unroll
    for (int j = 0; j < 32; j += 8)
      WT[(size_t)(bc + ty + j) * HIDN + bk + tx] = (__bf16)tl[tx][ty + j];
  }
}

// ---- fused: proj GEMM split-K=2 (704 blocks) + Wo^T transpose (4096) ------

__global__ __launch_bounds__(256) void k_proj_wo(
    const __bf16* __restrict__ A, const __bf16* __restrict__ BT,
    float* __restrict__ C0, float* __restrict__ C1,
    const float* __restrict__ Wo, __bf16* __restrict__ WoT) {
  __shared__ char smem[49152];            // GEMM: As 32KB | Bs 16KB ; WoT: 4.2KB
  const int bid = blockIdx.x;
  if (bid >= 704) {                       // ---- Wo^T [2048][2048] tile
    const int t = bid - 704;
    const int bn = (t % 64) * 32, bk = (t / 64) * 32;
    float (*tl)[33] = (float(*)[33])smem;
    const int tx = threadIdx.x & 31, ty = threadIdx.x >> 5;
#pragma unroll
    for (int j = 0; j < 32; j += 8)
      tl[ty + j][tx] = Wo[(size_t)(bk + ty + j) * HIDN + bn + tx];
    __syncthreads();
#pragma unroll
    for (int j = 0; j < 32; j += 8)
      WoT[(size_t)(bn + ty + j) * HIDN + bk + tx] = (__bf16)tl[tx][ty + j];
    return;
  }
  // ---- proj GEMM: C[2048][1408] = A[2048][2048] * BT[1408][2048]^T
  const int K = HIDN, N = NCOLS;
  __bf16* As = (__bf16*)smem;             // [4][4096]
  __bf16* Bs = (__bf16*)(smem + 32768);   // [4][2048]
  const int tid = threadIdx.x;
  const int w = tid >> 6, lane = tid & 63;
  const int lhi = lane >> 4, llo = lane & 15;
  const int wr = w >> 1, wc = w & 1;
  const int z = (bid >= 352);
  const int b = bid - z * 352;
  float* C = z ? C1 : C0;
  const int kbase = z * (K >> 1);
  const int sid = (b & 7) * 44 + (b >> 3);   // chunk swizzle (352 % 8 == 0)
  const int brow = (sid / 22) * 128, bcol = (sid % 22) * 64;
  const int rA = lane >> 2, kA = (lane & 3) * 8;
  const int nt = K >> 6;                  // 32 K-steps per half

  f32x4 acc[4][2];
#pragma unroll
  for (int m = 0; m < 4; m++)
#pragma unroll
    for (int n = 0; n < 2; n++) acc[m][n] = (f32x4){0.f, 0.f, 0.f, 0.f};

  auto stage = [&](int t) {               // 3 gload_lds per wave
    const int buf = t & 3;
    const int k0 = kbase + t * 32;
#pragma unroll
    for (int i = 0; i < 2; i++) {
      int seg = w * 2 + i;
      int row = seg * 16 + rA;
      gload_lds16(A + (size_t)(brow + row) * K + k0 + kA,
                  As + buf * 4096 + seg * 512);
    }
    gload_lds16(BT + (size_t)(bcol + w * 16 + rA) * K + k0 + kA,
                Bs + buf * 2048 + w * 512);
  };

  stage(0); stage(1); stage(2);
  asm volatile("s_waitcnt vmcnt(6)" ::: "memory");
  __builtin_amdgcn_s_barrier();

  for (int t = 0; t < nt; t++) {
    if (t + 3 < nt) stage(t + 3);
    const int buf = t & 3;
    bf16x8 af[4], bfr[2];
#pragma unroll
    for (int m = 0; m < 4; m++)
      af[m] = *(const bf16x8*)&As[buf * 4096 + (wr * 64 + m * 16 + llo) * 32 + lhi * 8];
#pragma unroll
    for (int n = 0; n < 2; n++)
      bfr[n] = *(const bf16x8*)&Bs[buf * 2048 + (wc * 32 + n * 16 + llo) * 32 + lhi * 8];
#pragma unroll
    for (int m = 0; m < 4; m++)
#pragma unroll
      for (int n = 0; n < 2; n++) acc[m][n] = MFMA(af[m], bfr[n], acc[m][n]);
    const int rem = nt - 2 - t;
    if (rem >= 2)      asm volatile("s_waitcnt vmcnt(6)" ::: "memory");
    else if (rem == 1) asm volatile("s_waitcnt vmcnt(3)" ::: "memory");
    else               asm volatile("s_waitcnt vmcnt(0)" ::: "memory");
    __builtin_amdgcn_s_barrier();
  }

#pragma unroll
  for (int m = 0; m < 4; m++)
#pragma unroll
    for (int n = 0; n < 2; n++) {
      int r0 = brow + wr * 64 + m * 16 + lhi * 4;
      int c0 = bcol + wc * 32 + n * 16 + llo;
#pragma unroll
      for (int r = 0; r < 4; r++) C[(size_t)(r0 + r) * N + c0] = acc[m][n][r];
    }
}

// ---- out GEMM: 128x128 tile, 8 waves (2x4), 512 threads, 4-deep pipeline --

__global__ __launch_bounds__(512) void k_gemm_out(const __bf16* __restrict__ A,
                                                  const __bf16* __restrict__ BT,
                                                  float* __restrict__ C) {
  __shared__ __bf16 As[4][4096];  // [buf][128 rows][32 k]
  __shared__ __bf16 Bs[4][4096];  // [buf][128 cols][32 k]
  const int K = HIDN, N = HIDN;
  const int tid = threadIdx.x;
  const int w = tid >> 6, lane = tid & 63;
  const int lhi = lane >> 4, llo = lane & 15;
  const int wr = w >> 2, wc = w & 3;

  // 2D region per XCD: 8 rows x 4 cols of 128x128 tiles
  const int id = blockIdx.y * 16 + blockIdx.x;
  const int g = id & 7, kk = id >> 3;     // kk 0..31
  const int rg = g >> 2, cg = g & 3;
  const int brow = (rg * 8 + (kk & 7)) * 128;
  const int bcol = (cg * 4 + (kk >> 3)) * 128;

  const int rA = tid >> 2, kA = (tid & 3) * 8;  // thread -> (row, k-chunk)
  const int nt = K >> 5;                        // 64

  f32x4 acc[4][2];
#pragma unroll
  for (int m = 0; m < 4; m++)
#pragma unroll
    for (int n = 0; n < 2; n++) acc[m][n] = (f32x4){0.f, 0.f, 0.f, 0.f};

  auto stage = [&](int t) {               // 2 gload_lds per wave
    const int buf = t & 3;
    const int k0 = t * 32;
    gload_lds16(A  + (size_t)(brow + rA) * K + k0 + kA, &As[buf][w * 512]);
    gload_lds16(BT + (size_t)(bcol + rA) * K + k0 + kA, &Bs[buf][w * 512]);
  };

  stage(0); stage(1); stage(2);
  asm volatile("s_waitcnt vmcnt(4)" ::: "memory");   // tile 0 landed
  __builtin_amdgcn_s_barrier();

  for (int t = 0; t < nt; t++) {
    if (t + 3 < nt) stage(t + 3);
    const int buf = t & 3;
    bf16x8 af[4], bfr[2];
#pragma unroll
    for (int m = 0; m < 4; m++)
      af[m] = *(const bf16x8*)&As[buf][(wr * 64 + m * 16 + llo) * 32 + lhi * 8];
#pragma unroll
    for (int n = 0; n < 2; n++)
      bfr[n] = *(const bf16x8*)&Bs[buf][(wc * 32 + n * 16 + llo) * 32 + lhi * 8];
#pragma unroll
    for (int m = 0; m < 4; m++)
#pragma unroll
      for (int n = 0; n < 2; n++) acc[m][n] = MFMA(af[m], bfr[n], acc[m][n]);
    const int rem = nt - 2 - t;
    if (rem >= 2)      asm volatile("s_waitcnt vmcnt(4)" ::: "memory");
    else if (rem == 1) asm volatile("s_waitcnt vmcnt(2)" ::: "memory");
    else               asm volatile("s_waitcnt vmcnt(0)" ::: "memory");
    __builtin_amdgcn_s_barrier();
  }

#pragma unroll
  for (int m = 0; m < 4; m++)
#pragma unroll
    for (int n = 0; n < 2; n++) {
      int r0 = brow + wr * 64 + m * 16 + lhi * 4;
      int c0 = bcol + wc * 32 + n * 16 + llo;
#pragma unroll
      for (int r = 0; r < 4; r++) C[(size_t)(r0 + r) * N + c0] = acc[m][n][r];
    }
}

// ---- build Q/K/Vp from projection PARTIALS (sum + rope + rank contraction)

__global__ __launch_bounds__(128) void k_build_qkv(const float* __restrict__ P0,
                                                   const float* __restrict__ P1,
                                                   const float* __restrict__ cosT,
                                                   const float* __restrict__ sinT,
                                                   __bf16* __restrict__ Qo,
                                                   __bf16* __restrict__ Ko,
                                                   __bf16* __restrict__ Vto) {
  const int q = blockIdx.x, d = threadIdx.x;  // 128 threads
  __shared__ float Ash[128];                  // Aq(96) | Ak(16) | Av(16)
  const float* r0 = P0 + (size_t)q * NCOLS;
  const float* r1 = P1 + (size_t)q * NCOLS;
  auto rd = [&](int i) { return r0[i] + r1[i]; };  // merge split-K halves
  Ash[d] = rd(d);
  __syncthreads();
  const int m2 = (d >> 1) * 2;
  const bool odd = d & 1;
  const float c = cosT[q * 64 + (d >> 1)];
  const float s = sinT[q * 64 + (d >> 1)];

  float qacc[16];
#pragma unroll
  for (int h = 0; h < 16; h++) qacc[h] = 0.f;
#pragma unroll
  for (int r = 0; r < 6; r++) {
    float xe = rd(128 + r * 128 + m2);
    float xo = rd(128 + r * 128 + m2 + 1);
    float br = odd ? (xe * s + xo * c) : (xe * c - xo * s);
#pragma unroll
    for (int h = 0; h < 16; h++) qacc[h] += Ash[h * 6 + r] * br;
  }
#pragma unroll
  for (int h = 0; h < 16; h++)
    Qo[((size_t)h * SEQ + q) * DH + d] = (__bf16)(qacc[h] * 0.08838834764831845f);

  float kacc[8];
#pragma unroll
  for (int g = 0; g < 8; g++) kacc[g] = 0.f;
#pragma unroll
  for (int ss = 0; ss < 2; ss++) {
    float xe = rd(896 + ss * 128 + m2);
    float xo = rd(896 + ss * 128 + m2 + 1);
    float bs = odd ? (xe * s + xo * c) : (xe * c - xo * s);
#pragma unroll
    for (int g = 0; g < 8; g++) kacc[g] += Ash[96 + g * 2 + ss] * bs;
  }
#pragma unroll
  for (int g = 0; g < 8; g++)
    Ko[((size_t)g * SEQ + q) * DH + d] = (__bf16)kacc[g];

  float vacc[8];
#pragma unroll
  for (int g = 0; g < 8; g++) vacc[g] = 0.f;
#pragma unroll
  for (int u = 0; u < 2; u++) {
    float vu = rd(1152 + u * 128 + d);
#pragma unroll
    for (int g = 0; g < 8; g++) vacc[g] += Ash[112 + g * 2 + u] * vu;
  }
  // pi(k) = ((k&15)>>2)*8 + (k&3) + ((k&16)>>2)
  const int qp = (q & ~31) | (((q & 15) >> 2) * 8 + (q & 3) + ((q & 16) >> 2));
#pragma unroll
  for (int g = 0; g < 8; g++)
    Vto[((size_t)g * DH + d) * SEQ + qp] = (__bf16)vacc[g];
}

// ---- flash attention: 3-buffer, ONE barrier per tile, stage-after-barrier -
// split-KV parts=2, XCD-affine, swapped QK^T + in-register P, key-permuted V.
// Loop: {vmcnt(4|0) -> barrier -> stage(t+2) -> compute(t)}. WAR proof with
// 3 bufs: stage(t+2) writes buf (t-1)%3, last read by compute(t-1); a wave
// issues stage(t+2) only after passing barrier B_t, and every wave reaches
// B_t only after finishing compute(t-1) => race-free with one barrier/tile.
// RAW: each wave drains its own tile-t loads (vmcnt) BEFORE B_t, so after
// B_t all waves' K+V for tile t are visible. 48KB LDS (R16: occupancy ~25%
// at this size — no capacity cliff, unlike R17's 64KB -> 2 blocks/CU).

__global__ __launch_bounds__(256) void k_attn(const __bf16* __restrict__ Q,
                                              const __bf16* __restrict__ Kc,
                                              const __bf16* __restrict__ Vt,
                                              float* __restrict__ AOf0,
                                              float* __restrict__ AOf1,
                                              float* __restrict__ Ls) {
  const int raw = blockIdx.x;          // 0..1023
  const int g = raw & 7;               // XCD affinity
  const int j = raw >> 3;              // 0..127
  const int bqi = 31 - (j >> 2);       // heavy-first per XCD stripe
  const int hh = (j >> 1) & 1;
  const int p = j & 1;
  const int h = g * 2 + hh;
  const int w = threadIdx.x >> 6, lane = threadIdx.x & 63;
  const int lhi = lane >> 4, llo = lane & 15;
  const int q0 = bqi * 64 + w * 16;
  const int t0 = p * (bqi + 1), t1 = t0 + bqi + 1;  // half the causal tiles

  __shared__ __bf16 KVs[3][8192];    // 3 bufs x (8KB K swz | 8KB V perm)

  const __bf16* Qh = Q  + (size_t)h * SEQ * DH;
  const __bf16* Kg = Kc + (size_t)g * SEQ * DH;
  const __bf16* Vg = Vt + (size_t)g * DH * SEQ;
  float* AOc = p ? AOf1 : AOf0;

  bf16x8 aq[4];
#pragma unroll
  for (int c = 0; c < 4; c++)
    aq[c] = *(const bf16x8*)&Qh[(size_t)(q0 + llo) * DH + c * 32 + lhi * 8];

  f32x4 oacc[8];
  float lsum = 0.f;
#pragma unroll
  for (int n = 0; n < 8; n++) oacc[n] = (f32x4){0.f, 0.f, 0.f, 0.f};

  // PV B-frag read: one b128 at kslots lhi*8..+7, row d = n*16+llo.
  const int vb = llo * 64 + ((lhi ^ ((llo >> 1) & 3)) << 4);

  auto stage = [&](int t) {            // 4 gload_lds per wave
    const int kb = t * 32;
    __bf16* L = KVs[t % 3];
    if (w < 2) {
#pragma unroll
      for (int u = 0; u < 4; u++) {
        int c = w * 256 + u * 64 + lane;
        int row = c >> 4, jj = c & 15;
        gload_lds16(Kg + (size_t)(kb + row) * DH + ((jj ^ (row & 7)) * 8),
                    L + (w * 256 + u * 64) * 8);
      }
    } else {
#pragma unroll
      for (int u = 0; u < 4; u++) {
        int c = (w - 2) * 256 + u * 64 + lane;
        int d = c >> 2, jj = c & 3;
        gload_lds16(Vg + (size_t)d * SEQ + kb + ((jj ^ ((d >> 1) & 3)) * 8),
                    L + 4096 + ((w - 2) * 256 + u * 64) * 8);
      }
    }
  };

  stage(t0);
  if (t0 + 1 < t1) stage(t0 + 1);
  for (int t = t0; t < t1; t++) {
    const int kb = t * 32;
    const int buf = t % 3;
    if (t + 1 < t1) {
      asm volatile("s_waitcnt vmcnt(4)" ::: "memory");  // tile t landed
    } else {
      asm volatile("s_waitcnt vmcnt(0)" ::: "memory");
    }
    __builtin_amdgcn_s_barrier();        // the ONLY barrier per tile
    if (t + 2 < t1) stage(t + 2);        // after barrier: overwrites buf
                                         // (t-1)%3, done being read by all
    if (kb <= q0 + 15) {   // wave-uniform skip of fully-masked tiles
      const char* Kl = (const char*)KVs[buf];
      const char* Vl = (const char*)(KVs[buf] + 4096);
      f32x4 s0 = {0.f, 0.f, 0.f, 0.f}, s1 = {0.f, 0.f, 0.f, 0.f};
#pragma unroll
      for (int c = 0; c < 4; c++) {
        const int row0 = llo, row1 = 16 + llo;
        bf16x8 k0 = *(const bf16x8*)(Kl + row0 * 256 +
                                     ((c * 64 + lhi * 16) ^ ((row0 & 7) << 4)));
        bf16x8 k1 = *(const bf16x8*)(Kl + row1 * 256 +
                                     ((c * 64 + lhi * 16) ^ ((row1 & 7) << 4)));
        s0 = MFMA(k0, aq[c], s0);   // swapped: S^T[key][q]
        s1 = MFMA(k1, aq[c], s1);
      }
      float e[8];
#pragma unroll
      for (int r = 0; r < 4; r++) {
        float a0 = exp2f(s0[r] * 0.057707802f);
        float a1 = exp2f(s1[r] * 0.057707802f);
        e[r]     = exp2f(72.134752f - 144.269504f * __builtin_amdgcn_rcpf(a0 + 1.f));
        e[4 + r] = exp2f(72.134752f - 144.269504f * __builtin_amdgcn_rcpf(a1 + 1.f));
      }
      if (kb + 31 > q0) {          // diagonal tile only: causal mask
        const int qrow = q0 + llo;
#pragma unroll
        for (int r = 0; r < 4; r++) {
          if (kb + lhi * 4 + r > qrow)      e[r] = 0.f;
          if (kb + 16 + lhi * 4 + r > qrow) e[4 + r] = 0.f;
        }
      }
#pragma unroll
      for (int r = 0; r < 4; r++) lsum += e[r] + e[4 + r];
      union { bf16x8 v8; unsigned u[4]; } pu;
      asm("v_cvt_pk_bf16_f32 %0, %1, %2" : "=v"(pu.u[0]) : "v"(e[0]), "v"(e[1]));
      asm("v_cvt_pk_bf16_f32 %0, %1, %2" : "=v"(pu.u[1]) : "v"(e[2]), "v"(e[3]));
      asm("v_cvt_pk_bf16_f32 %0, %1, %2" : "=v"(pu.u[2]) : "v"(e[4]), "v"(e[5]));
      asm("v_cvt_pk_bf16_f32 %0, %1, %2" : "=v"(pu.u[3]) : "v"(e[6]), "v"(e[7]));
#pragma unroll
      for (int n = 0; n < 8; n++) {
        bf16x8 vf = *(const bf16x8*)(Vl + vb + n * 1024);
        oacc[n] = MFMA(pu.v8, vf, oacc[n]);
      }
    }
  }

  float tsum = lsum;
  tsum += __shfl_xor(tsum, 16);
  tsum += __shfl_xor(tsum, 32);
  if (lhi == 0) Ls[((size_t)p * NHEAD + h) * SEQ + q0 + llo] = tsum;
#pragma unroll
  for (int r = 0; r < 4; r++) {
    const int qrow = q0 + lhi * 4 + r;
#pragma unroll
    for (int n = 0; n < 8; n++)
      AOc[(size_t)qrow * HIDN + h * DH + n * 16 + llo] = oacc[n][r];
  }
}

// ---- merge split-KV partials, normalize, cast to bf16 ---------------------

__global__ __launch_bounds__(256) void k_norm(const float* __restrict__ A0,
                                              const float* __restrict__ A1,
                                              const float* __restrict__ Ls,
                                              __bf16* __restrict__ AO) {
  const int i = (blockIdx.x * 256 + threadIdx.x) * 4;  // 4M elems, f32x4
  const int q = i >> 11, h = (i & 2047) >> 7;
  const float inv = 1.f / (Ls[h * SEQ + q] + Ls[(NHEAD + h) * SEQ + q]);
  f32x4 a = *(const f32x4*)(A0 + i);
  f32x4 b = *(const f32x4*)(A1 + i);
#pragma unroll
  for (int j = 0; j < 4; j++) AO[i + j] = (__bf16)((a[j] + b[j]) * inv);
}

// ---------------------------------------------------------------------------

extern "C" void kernel_launch(void* const* d_in, const int* in_sizes, int n_in,
                              void* d_out, int out_size, void* d_ws, size_t ws_size,
                              hipStream_t stream) {
  const float* hidden = (const float*)d_in[0];
  const float* cosT   = (const float*)d_in[1];
  const float* sinT   = (const float*)d_in[2];
  // d_in[3] = mask (pure causal, computed analytically), d_in[4] = arange (unused)
  const float* WAq = (const float*)d_in[5];
  const float* WAk = (const float*)d_in[6];
  const float* WAv = (const float*)d_in[7];
  const float* WBq = (const float*)d_in[8];
  const float* WBk = (const float*)d_in[9];
  const float* WBv = (const float*)d_in[10];
  const float* Wo  = (const float*)d_in[11];
  float* out = (float*)d_out;

  // Workspace layout (lifetime-aliased), ~67.9 MB:
  //   [0)          hid_bf (8.39M)  -> AOf0 (16.78M) after proj is done
  //   [8388608)    WallT  (5.77M)      (overlaid by AOf0)
  //   [14155776)   Pp0    (11.53M)     (first 2.6M overlaid by AOf0; dead
  //                                     after build_qkv)
  //   [25690112)   WoT    (8.39M)      (live until final GEMM)
  //   [34078720)   Qb     (8.39M)  -> AO bf16 after attn is done
  //   [42467328)   Kb     (4.19M)
  //   [46661632)   Vt     (4.19M)
  //   [50855936)   Pp1    (11.53M) -> AOf1 (16.78M) after build_qkv is done
  //   [67633152)   Ls     (0.26M)
  char* ws = (char*)d_ws;
  __bf16* hid_bf = (__bf16*)(ws);
  __bf16* WallT  = (__bf16*)(ws + 8388608);
  float*  Pp0    = (float*)(ws + 14155776);
  __bf16* WoT    = (__bf16*)(ws + 25690112);
  __bf16* Qb     = (__bf16*)(ws + 34078720);
  __bf16* Kb     = (__bf16*)(ws + 42467328);
  __bf16* Vt     = (__bf16*)(ws + 46661632);
  float*  Pp1    = (float*)(ws + 50855936);
  float*  AOf0   = (float*)(ws);
  float*  AOf1   = (float*)(ws + 50855936);
  float*  Ls     = (float*)(ws + 67633152);
  __bf16* AO     = (__bf16*)(ws + 34078720);  // aliases Qb (dead after attn)

  // prep: 2048 cvt blocks + 44*64 wall-transpose
  k_prep<<<2048 + 44 * 64, 256, 0, stream>>>(
      hidden, WAq, WAk, WAv, WBq, WBk, WBv, hid_bf, WallT);
  // proj GEMM split-K=2 (704 blocks) + WoT transpose (4096 blocks) fused
  k_proj_wo<<<704 + 4096, 256, 0, stream>>>(hid_bf, WallT, Pp0, Pp1, Wo, WoT);
  k_build_qkv<<<SEQ, 128, 0, stream>>>(Pp0, Pp1, cosT, sinT, Qb, Kb, Vt);
  k_attn<<<1024, 256, 0, stream>>>(Qb, Kb, Vt, AOf0, AOf1, Ls);
  k_norm<<<(SEQ * HIDN / 4) / 256, 256, 0, stream>>>(AOf0, AOf1, Ls, AO);
  k_gemm_out<<<dim3(16, 16), 512, 0, stream>>>(AO, WoT, out);
}

// Round 19
// 148.223 us; speedup vs baseline: 1.0708x; 1.0207x over previous
//
#include <hip/hip_runtime.h>

// ---------------------------------------------------------------------------
// TPA attention, factorized to GQA flash attention.
// B=1, S=2048, HID=2048, H=16, KVH=8, D=128, QR=6, KR=2, VR=2
// ---------------------------------------------------------------------------

constexpr int SEQ   = 2048;
constexpr int HIDN  = 2048;
constexpr int NHEAD = 16;
constexpr int NKVH  = 8;
constexpr int DH    = 128;
constexpr int NCOLS = 1408;   // 96 Aq | 16 Ak | 16 Av | 768 Bq | 256 Bk | 256 Bv

typedef __bf16 bf16x8 __attribute__((ext_vector_type(8)));
typedef float  f32x4  __attribute__((ext_vector_type(4)));

#define MFMA(a, b, c) __builtin_amdgcn_mfma_f32_16x16x32_bf16((a), (b), (c), 0, 0, 0)

__device__ __forceinline__ void gload_lds16(const void* g, void* l) {
  __builtin_amdgcn_global_load_lds(
      (const __attribute__((address_space(1))) void*)g,
      (__attribute__((address_space(3))) void*)l, 16, 0, 0);
}

// ---- prep: hidden cvt + W_all^T transpose (WoT lives in proj launch) ------

__global__ __launch_bounds__(256) void k_prep(
    const float* __restrict__ hidden,
    const float* __restrict__ WAq, const float* __restrict__ WAk,
    const float* __restrict__ WAv, const float* __restrict__ WBq,
    const float* __restrict__ WBk, const float* __restrict__ WBv,
    __bf16* __restrict__ hid_bf, __bf16* __restrict__ WT) {
  const int bid = blockIdx.x;
  if (bid < 2048) {                       // ---- hidden f32 -> bf16, x8
    const int i = (bid * 256 + threadIdx.x) * 8;
    f32x4 a = *(const f32x4*)(hidden + i);
    f32x4 b = *(const f32x4*)(hidden + i + 4);
    bf16x8 v;
#pragma unroll
    for (int j = 0; j < 4; j++) { v[j] = (__bf16)a[j]; v[4 + j] = (__bf16)b[j]; }
    *(bf16x8*)(hid_bf + i) = v;
  } else {                                // ---- W_all^T [1408][2048]
    const int t = bid - 2048;             // t < 44*64
    const int bc = (t % 44) * 32, bk = (t / 44) * 32;
    __shared__ float tl[32][33];
    const int tx = threadIdx.x & 31, ty = threadIdx.x >> 5;  // ty 0..7
    const int c = bc + tx;
#pragma unroll
    for (int j = 0; j < 32; j += 8) {
      const int k = bk + ty + j;
      float v;
      if (c < 96)        v = WAq[k * 96 + c];
      else if (c < 112)  v = WAk[k * 16 + (c - 96)];
      else if (c < 128)  v = WAv[k * 16 + (c - 112)];
      else if (c < 896)  v = WBq[k * 768 + (c - 128)];
      else if (c < 1152) v = WBk[k * 256 + (c - 896)];
      else               v = WBv[k * 256 + (c - 1152)];
      tl[ty + j][tx] = v;                 // tl[k-local][c-local]
    }
    __syncthreads();
#pragma unroll
    for (int j = 0; j < 32; j += 8)
      WT[(size_t)(bc + ty + j) * HIDN + bk + tx] = (__bf16)tl[tx][ty + j];
  }
}

// ---- fused: proj GEMM split-K=2 (704 blocks) + Wo^T transpose (4096) ------

__global__ __launch_bounds__(256) void k_proj_wo(
    const __bf16* __restrict__ A, const __bf16* __restrict__ BT,
    float* __restrict__ C0, float* __restrict__ C1,
    const float* __restrict__ Wo, __bf16* __restrict__ WoT) {
  __shared__ char smem[49152];            // GEMM: As 32KB | Bs 16KB ; WoT: 4.2KB
  const int bid = blockIdx.x;
  if (bid >= 704) {                       // ---- Wo^T [2048][2048] tile
    const int t = bid - 704;
    const int bn = (t % 64) * 32, bk = (t / 64) * 32;
    float (*tl)[33] = (float(*)[33])smem;
    const int tx = threadIdx.x & 31, ty = threadIdx.x >> 5;
#pragma unroll
    for (int j = 0; j < 32; j += 8)
      tl[ty + j][tx] = Wo[(size_t)(bk + ty + j) * HIDN + bn + tx];
    __syncthreads();
#pragma unroll
    for (int j = 0; j < 32; j += 8)
      WoT[(size_t)(bn + ty + j) * HIDN + bk + tx] = (__bf16)tl[tx][ty + j];
    return;
  }
  // ---- proj GEMM: C[2048][1408] = A[2048][2048] * BT[1408][2048]^T
  const int K = HIDN, N = NCOLS;
  __bf16* As = (__bf16*)smem;             // [4][4096]
  __bf16* Bs = (__bf16*)(smem + 32768);   // [4][2048]
  const int tid = threadIdx.x;
  const int w = tid >> 6, lane = tid & 63;
  const int lhi = lane >> 4, llo = lane & 15;
  const int wr = w >> 1, wc = w & 1;
  const int z = (bid >= 352);
  const int b = bid - z * 352;
  float* C = z ? C1 : C0;
  const int kbase = z * (K >> 1);
  const int sid = (b & 7) * 44 + (b >> 3);   // chunk swizzle (352 % 8 == 0)
  const int brow = (sid / 22) * 128, bcol = (sid % 22) * 64;
  const int rA = lane >> 2, kA = (lane & 3) * 8;
  const int nt = K >> 6;                  // 32 K-steps per half

  f32x4 acc[4][2];
#pragma unroll
  for (int m = 0; m < 4; m++)
#pragma unroll
    for (int n = 0; n < 2; n++) acc[m][n] = (f32x4){0.f, 0.f, 0.f, 0.f};

  auto stage = [&](int t) {               // 3 gload_lds per wave
    const int buf = t & 3;
    const int k0 = kbase + t * 32;
#pragma unroll
    for (int i = 0; i < 2; i++) {
      int seg = w * 2 + i;
      int row = seg * 16 + rA;
      gload_lds16(A + (size_t)(brow + row) * K + k0 + kA,
                  As + buf * 4096 + seg * 512);
    }
    gload_lds16(BT + (size_t)(bcol + w * 16 + rA) * K + k0 + kA,
                Bs + buf * 2048 + w * 512);
  };

  stage(0); stage(1); stage(2);
  asm volatile("s_waitcnt vmcnt(6)" ::: "memory");
  __builtin_amdgcn_s_barrier();

  for (int t = 0; t < nt; t++) {
    if (t + 3 < nt) stage(t + 3);
    const int buf = t & 3;
    bf16x8 af[4], bfr[2];
#pragma unroll
    for (int m = 0; m < 4; m++)
      af[m] = *(const bf16x8*)&As[buf * 4096 + (wr * 64 + m * 16 + llo) * 32 + lhi * 8];
#pragma unroll
    for (int n = 0; n < 2; n++)
      bfr[n] = *(const bf16x8*)&Bs[buf * 2048 + (wc * 32 + n * 16 + llo) * 32 + lhi * 8];
#pragma unroll
    for (int m = 0; m < 4; m++)
#pragma unroll
      for (int n = 0; n < 2; n++) acc[m][n] = MFMA(af[m], bfr[n], acc[m][n]);
    const int rem = nt - 2 - t;
    if (rem >= 2)      asm volatile("s_waitcnt vmcnt(6)" ::: "memory");
    else if (rem == 1) asm volatile("s_waitcnt vmcnt(3)" ::: "memory");
    else               asm volatile("s_waitcnt vmcnt(0)" ::: "memory");
    __builtin_amdgcn_s_barrier();
  }

#pragma unroll
  for (int m = 0; m < 4; m++)
#pragma unroll
    for (int n = 0; n < 2; n++) {
      int r0 = brow + wr * 64 + m * 16 + lhi * 4;
      int c0 = bcol + wc * 32 + n * 16 + llo;
#pragma unroll
      for (int r = 0; r < 4; r++) C[(size_t)(r0 + r) * N + c0] = acc[m][n][r];
    }
}

// ---- out GEMM: 128x128 tile, 8 waves (2x4), 512 threads, 4-deep pipeline --

__global__ __launch_bounds__(512) void k_gemm_out(const __bf16* __restrict__ A,
                                                  const __bf16* __restrict__ BT,
                                                  float* __restrict__ C) {
  __shared__ __bf16 As[4][4096];  // [buf][128 rows][32 k]
  __shared__ __bf16 Bs[4][4096];  // [buf][128 cols][32 k]
  const int K = HIDN, N = HIDN;
  const int tid = threadIdx.x;
  const int w = tid >> 6, lane = tid & 63;
  const int lhi = lane >> 4, llo = lane & 15;
  const int wr = w >> 2, wc = w & 3;

  // 2D region per XCD: 8 rows x 4 cols of 128x128 tiles
  const int id = blockIdx.y * 16 + blockIdx.x;
  const int g = id & 7, kk = id >> 3;     // kk 0..31
  const int rg = g >> 2, cg = g & 3;
  const int brow = (rg * 8 + (kk & 7)) * 128;
  const int bcol = (cg * 4 + (kk >> 3)) * 128;

  const int rA = tid >> 2, kA = (tid & 3) * 8;  // thread -> (row, k-chunk)
  const int nt = K >> 5;                        // 64

  f32x4 acc[4][2];
#pragma unroll
  for (int m = 0; m < 4; m++)
#pragma unroll
    for (int n = 0; n < 2; n++) acc[m][n] = (f32x4){0.f, 0.f, 0.f, 0.f};

  auto stage = [&](int t) {               // 2 gload_lds per wave
    const int buf = t & 3;
    const int k0 = t * 32;
    gload_lds16(A  + (size_t)(brow + rA) * K + k0 + kA, &As[buf][w * 512]);
    gload_lds16(BT + (size_t)(bcol + rA) * K + k0 + kA, &Bs[buf][w * 512]);
  };

  stage(0); stage(1); stage(2);
  asm volatile("s_waitcnt vmcnt(4)" ::: "memory");   // tile 0 landed
  __builtin_amdgcn_s_barrier();

  for (int t = 0; t < nt; t++) {
    if (t + 3 < nt) stage(t + 3);
    const int buf = t & 3;
    bf16x8 af[4], bfr[2];
#pragma unroll
    for (int m = 0; m < 4; m++)
      af[m] = *(const bf16x8*)&As[buf][(wr * 64 + m * 16 + llo) * 32 + lhi * 8];
#pragma unroll
    for (int n = 0; n < 2; n++)
      bfr[n] = *(const bf16x8*)&Bs[buf][(wc * 32 + n * 16 + llo) * 32 + lhi * 8];
#pragma unroll
    for (int m = 0; m < 4; m++)
#pragma unroll
      for (int n = 0; n < 2; n++) acc[m][n] = MFMA(af[m], bfr[n], acc[m][n]);
    const int rem = nt - 2 - t;
    if (rem >= 2)      asm volatile("s_waitcnt vmcnt(4)" ::: "memory");
    else if (rem == 1) asm volatile("s_waitcnt vmcnt(2)" ::: "memory");
    else               asm volatile("s_waitcnt vmcnt(0)" ::: "memory");
    __builtin_amdgcn_s_barrier();
  }

#pragma unroll
  for (int m = 0; m < 4; m++)
#pragma unroll
    for (int n = 0; n < 2; n++) {
      int r0 = brow + wr * 64 + m * 16 + lhi * 4;
      int c0 = bcol + wc * 32 + n * 16 + llo;
#pragma unroll
      for (int r = 0; r < 4; r++) C[(size_t)(r0 + r) * N + c0] = acc[m][n][r];
    }
}

// ---- build Q/K/Vp from projection PARTIALS (sum + rope + rank contraction)

__global__ __launch_bounds__(128) void k_build_qkv(const float* __restrict__ P0,
                                                   const float* __restrict__ P1,
                                                   const float* __restrict__ cosT,
                                                   const float* __restrict__ sinT,
                                                   __bf16* __restrict__ Qo,
                                                   __bf16* __restrict__ Ko,
                                                   __bf16* __restrict__ Vto) {
  const int q = blockIdx.x, d = threadIdx.x;  // 128 threads
  __shared__ float Ash[128];                  // Aq(96) | Ak(16) | Av(16)
  const float* r0 = P0 + (size_t)q * NCOLS;
  const float* r1 = P1 + (size_t)q * NCOLS;
  auto rd = [&](int i) { return r0[i] + r1[i]; };  // merge split-K halves
  Ash[d] = rd(d);
  __syncthreads();
  const int m2 = (d >> 1) * 2;
  const bool odd = d & 1;
  const float c = cosT[q * 64 + (d >> 1)];
  const float s = sinT[q * 64 + (d >> 1)];

  float qacc[16];
#pragma unroll
  for (int h = 0; h < 16; h++) qacc[h] = 0.f;
#pragma unroll
  for (int r = 0; r < 6; r++) {
    float xe = rd(128 + r * 128 + m2);
    float xo = rd(128 + r * 128 + m2 + 1);
    float br = odd ? (xe * s + xo * c) : (xe * c - xo * s);
#pragma unroll
    for (int h = 0; h < 16; h++) qacc[h] += Ash[h * 6 + r] * br;
  }
#pragma unroll
  for (int h = 0; h < 16; h++)
    Qo[((size_t)h * SEQ + q) * DH + d] = (__bf16)(qacc[h] * 0.08838834764831845f);

  float kacc[8];
#pragma unroll
  for (int g = 0; g < 8; g++) kacc[g] = 0.f;
#pragma unroll
  for (int ss = 0; ss < 2; ss++) {
    float xe = rd(896 + ss * 128 + m2);
    float xo = rd(896 + ss * 128 + m2 + 1);
    float bs = odd ? (xe * s + xo * c) : (xe * c - xo * s);
#pragma unroll
    for (int g = 0; g < 8; g++) kacc[g] += Ash[96 + g * 2 + ss] * bs;
  }
#pragma unroll
  for (int g = 0; g < 8; g++)
    Ko[((size_t)g * SEQ + q) * DH + d] = (__bf16)kacc[g];

  float vacc[8];
#pragma unroll
  for (int g = 0; g < 8; g++) vacc[g] = 0.f;
#pragma unroll
  for (int u = 0; u < 2; u++) {
    float vu = rd(1152 + u * 128 + d);
#pragma unroll
    for (int g = 0; g < 8; g++) vacc[g] += Ash[112 + g * 2 + u] * vu;
  }
  // pi(k) = ((k&15)>>2)*8 + (k&3) + ((k&16)>>2)
  const int qp = (q & ~31) | (((q & 15) >> 2) * 8 + (q & 3) + ((q & 16) >> 2));
#pragma unroll
  for (int g = 0; g < 8; g++)
    Vto[((size_t)g * DH + d) * SEQ + qp] = (__bf16)vacc[g];
}

// ---- flash attention (R15 structure — proven best) + setprio --------------
// split-KV parts=2, XCD-affine, 2-buffer staged (vmcnt(4) counted), swapped
// QK^T + in-register P, key-permuted V (single bank-balanced ds_read_b128).
// ONLY change vs R15: s_setprio(1) around the QK and PV MFMA clusters (T5) —
// isolated A/B (R16 bundled it with the 3-buf change; R18 showed that
// family costs ~2us, so setprio's own effect was never measured).

__global__ __launch_bounds__(256) void k_attn(const __bf16* __restrict__ Q,
                                              const __bf16* __restrict__ Kc,
                                              const __bf16* __restrict__ Vt,
                                              float* __restrict__ AOf0,
                                              float* __restrict__ AOf1,
                                              float* __restrict__ Ls) {
  const int raw = blockIdx.x;          // 0..1023
  const int g = raw & 7;               // XCD affinity
  const int j = raw >> 3;              // 0..127
  const int bqi = 31 - (j >> 2);       // heavy-first per XCD stripe
  const int hh = (j >> 1) & 1;
  const int p = j & 1;
  const int h = g * 2 + hh;
  const int w = threadIdx.x >> 6, lane = threadIdx.x & 63;
  const int lhi = lane >> 4, llo = lane & 15;
  const int q0 = bqi * 64 + w * 16;
  const int t0 = p * (bqi + 1), t1 = t0 + bqi + 1;  // half the causal tiles

  __shared__ __bf16 KVs[2][8192];    // 8KB K (32x128 swz) | 8KB V (128x32 perm)

  const __bf16* Qh = Q  + (size_t)h * SEQ * DH;
  const __bf16* Kg = Kc + (size_t)g * SEQ * DH;
  const __bf16* Vg = Vt + (size_t)g * DH * SEQ;
  float* AOc = p ? AOf1 : AOf0;

  bf16x8 aq[4];
#pragma unroll
  for (int c = 0; c < 4; c++)
    aq[c] = *(const bf16x8*)&Qh[(size_t)(q0 + llo) * DH + c * 32 + lhi * 8];

  f32x4 oacc[8];
  float lsum = 0.f;
#pragma unroll
  for (int n = 0; n < 8; n++) oacc[n] = (f32x4){0.f, 0.f, 0.f, 0.f};

  // PV B-frag read: one b128 at kslots lhi*8..+7, row d = n*16+llo.
  const int vb = llo * 64 + ((lhi ^ ((llo >> 1) & 3)) << 4);

  auto stage = [&](int kb, int buf) {
    __bf16* L = KVs[buf];
    if (w < 2) {
#pragma unroll
      for (int u = 0; u < 4; u++) {
        int c = w * 256 + u * 64 + lane;
        int row = c >> 4, jj = c & 15;
        gload_lds16(Kg + (size_t)(kb + row) * DH + ((jj ^ (row & 7)) * 8),
                    L + (w * 256 + u * 64) * 8);
      }
    } else {
#pragma unroll
      for (int u = 0; u < 4; u++) {
        int c = (w - 2) * 256 + u * 64 + lane;
        int d = c >> 2, jj = c & 3;
        gload_lds16(Vg + (size_t)d * SEQ + kb + ((jj ^ ((d >> 1) & 3)) * 8),
                    L + 4096 + ((w - 2) * 256 + u * 64) * 8);
      }
    }
  };

  stage(t0 * 32, t0 & 1);
  for (int t = t0; t < t1; t++) {
    const int kb = t * 32;
    const int buf = t & 1;
    if (t + 1 < t1) {
      stage(kb + 32, buf ^ 1);
      asm volatile("s_waitcnt vmcnt(4)" ::: "memory");  // cur tile staged
    } else {
      asm volatile("s_waitcnt vmcnt(0)" ::: "memory");
    }
    __builtin_amdgcn_s_barrier();
    if (kb <= q0 + 15) {   // wave-uniform skip of fully-masked tiles
      const char* Kl = (const char*)KVs[buf];
      const char* Vl = (const char*)(KVs[buf] + 4096);
      f32x4 s0 = {0.f, 0.f, 0.f, 0.f}, s1 = {0.f, 0.f, 0.f, 0.f};
      __builtin_amdgcn_s_setprio(1);
#pragma unroll
      for (int c = 0; c < 4; c++) {
        const int row0 = llo, row1 = 16 + llo;
        bf16x8 k0 = *(const bf16x8*)(Kl + row0 * 256 +
                                     ((c * 64 + lhi * 16) ^ ((row0 & 7) << 4)));
        bf16x8 k1 = *(const bf16x8*)(Kl + row1 * 256 +
                                     ((c * 64 + lhi * 16) ^ ((row1 & 7) << 4)));
        s0 = MFMA(k0, aq[c], s0);   // swapped: S^T[key][q]
        s1 = MFMA(k1, aq[c], s1);
      }
      __builtin_amdgcn_s_setprio(0);
      float e[8];
#pragma unroll
      for (int r = 0; r < 4; r++) {
        float a0 = exp2f(s0[r] * 0.057707802f);
        float a1 = exp2f(s1[r] * 0.057707802f);
        e[r]     = exp2f(72.134752f - 144.269504f * __builtin_amdgcn_rcpf(a0 + 1.f));
        e[4 + r] = exp2f(72.134752f - 144.269504f * __builtin_amdgcn_rcpf(a1 + 1.f));
      }
      if (kb + 31 > q0) {          // diagonal tile only: causal mask
        const int qrow = q0 + llo;
#pragma unroll
        for (int r = 0; r < 4; r++) {
          if (kb + lhi * 4 + r > qrow)      e[r] = 0.f;
          if (kb + 16 + lhi * 4 + r > qrow) e[4 + r] = 0.f;
        }
      }
#pragma unroll
      for (int r = 0; r < 4; r++) lsum += e[r] + e[4 + r];
      union { bf16x8 v8; unsigned u[4]; } pu;
      asm("v_cvt_pk_bf16_f32 %0, %1, %2" : "=v"(pu.u[0]) : "v"(e[0]), "v"(e[1]));
      asm("v_cvt_pk_bf16_f32 %0, %1, %2" : "=v"(pu.u[1]) : "v"(e[2]), "v"(e[3]));
      asm("v_cvt_pk_bf16_f32 %0, %1, %2" : "=v"(pu.u[2]) : "v"(e[4]), "v"(e[5]));
      asm("v_cvt_pk_bf16_f32 %0, %1, %2" : "=v"(pu.u[3]) : "v"(e[6]), "v"(e[7]));
      __builtin_amdgcn_s_setprio(1);
#pragma unroll
      for (int n = 0; n < 8; n++) {
        bf16x8 vf = *(const bf16x8*)(Vl + vb + n * 1024);
        oacc[n] = MFMA(pu.v8, vf, oacc[n]);
      }
      __builtin_amdgcn_s_setprio(0);
    }
    asm volatile("" ::: "memory");
    __builtin_amdgcn_s_barrier();
  }

  float tsum = lsum;
  tsum += __shfl_xor(tsum, 16);
  tsum += __shfl_xor(tsum, 32);
  if (lhi == 0) Ls[((size_t)p * NHEAD + h) * SEQ + q0 + llo] = tsum;
#pragma unroll
  for (int r = 0; r < 4; r++) {
    const int qrow = q0 + lhi * 4 + r;
#pragma unroll
    for (int n = 0; n < 8; n++)
      AOc[(size_t)qrow * HIDN + h * DH + n * 16 + llo] = oacc[n][r];
  }
}

// ---- merge split-KV partials, normalize, cast to bf16 ---------------------

__global__ __launch_bounds__(256) void k_norm(const float* __restrict__ A0,
                                              const float* __restrict__ A1,
                                              const float* __restrict__ Ls,
                                              __bf16* __restrict__ AO) {
  const int i = (blockIdx.x * 256 + threadIdx.x) * 4;  // 4M elems, f32x4
  const int q = i >> 11, h = (i & 2047) >> 7;
  const float inv = 1.f / (Ls[h * SEQ + q] + Ls[(NHEAD + h) * SEQ + q]);
  f32x4 a = *(const f32x4*)(A0 + i);
  f32x4 b = *(const f32x4*)(A1 + i);
#pragma unroll
  for (int j = 0; j < 4; j++) AO[i + j] = (__bf16)((a[j] + b[j]) * inv);
}

// ---------------------------------------------------------------------------

extern "C" void kernel_launch(void* const* d_in, const int* in_sizes, int n_in,
                              void* d_out, int out_size, void* d_ws, size_t ws_size,
                              hipStream_t stream) {
  const float* hidden = (const float*)d_in[0];
  const float* cosT   = (const float*)d_in[1];
  const float* sinT   = (const float*)d_in[2];
  // d_in[3] = mask (pure causal, computed analytically), d_in[4] = arange (unused)
  const float* WAq = (const float*)d_in[5];
  const float* WAk = (const float*)d_in[6];
  const float* WAv = (const float*)d_in[7];
  const float* WBq = (const float*)d_in[8];
  const float* WBk = (const float*)d_in[9];
  const float* WBv = (const float*)d_in[10];
  const float* Wo  = (const float*)d_in[11];
  float* out = (float*)d_out;

  // Workspace layout (lifetime-aliased), ~67.9 MB:
  //   [0)          hid_bf (8.39M)  -> AOf0 (16.78M) after proj is done
  //   [8388608)    WallT  (5.77M)      (overlaid by AOf0)
  //   [14155776)   Pp0    (11.53M)     (first 2.6M overlaid by AOf0; dead
  //                                     after build_qkv)
  //   [25690112)   WoT    (8.39M)      (live until final GEMM)
  //   [34078720)   Qb     (8.39M)  -> AO bf16 after attn is done
  //   [42467328)   Kb     (4.19M)
  //   [46661632)   Vt     (4.19M)
  //   [50855936)   Pp1    (11.53M) -> AOf1 (16.78M) after build_qkv is done
  //   [67633152)   Ls     (0.26M)
  char* ws = (char*)d_ws;
  __bf16* hid_bf = (__bf16*)(ws);
  __bf16* WallT  = (__bf16*)(ws + 8388608);
  float*  Pp0    = (float*)(ws + 14155776);
  __bf16* WoT    = (__bf16*)(ws + 25690112);
  __bf16* Qb     = (__bf16*)(ws + 34078720);
  __bf16* Kb     = (__bf16*)(ws + 42467328);
  __bf16* Vt     = (__bf16*)(ws + 46661632);
  float*  Pp1    = (float*)(ws + 50855936);
  float*  AOf0   = (float*)(ws);
  float*  AOf1   = (float*)(ws + 50855936);
  float*  Ls     = (float*)(ws + 67633152);
  __bf16* AO     = (__bf16*)(ws + 34078720);  // aliases Qb (dead after attn)

  // prep: 2048 cvt blocks + 44*64 wall-transpose
  k_prep<<<2048 + 44 * 64, 256, 0, stream>>>(
      hidden, WAq, WAk, WAv, WBq, WBk, WBv, hid_bf, WallT);
  // proj GEMM split-K=2 (704 blocks) + WoT transpose (4096 blocks) fused
  k_proj_wo<<<704 + 4096, 256, 0, stream>>>(hid_bf, WallT, Pp0, Pp1, Wo, WoT);
  k_build_qkv<<<SEQ, 128, 0, stream>>>(Pp0, Pp1, cosT, sinT, Qb, Kb, Vt);
  k_attn<<<1024, 256, 0, stream>>>(Qb, Kb, Vt, AOf0, AOf1, Ls);
  k_norm<<<(SEQ * HIDN / 4) / 256, 256, 0, stream>>>(AOf0, AOf1, Ls, AO);
  k_gemm_out<<<dim3(16, 16), 512, 0, stream>>>(AO, WoT, out);
}

// Round 20
// 141.504 us; speedup vs baseline: 1.1216x; 1.0475x over previous
//
#include <hip/hip_runtime.h>

// ---------------------------------------------------------------------------
// TPA attention, factorized to GQA flash attention.
// B=1, S=2048, HID=2048, H=16, KVH=8, D=128, QR=6, KR=2, VR=2
// ---------------------------------------------------------------------------

constexpr int SEQ   = 2048;
constexpr int HIDN  = 2048;
constexpr int NHEAD = 16;
constexpr int NKVH  = 8;
constexpr int DH    = 128;
constexpr int NCOLS = 1408;   // 96 Aq | 16 Ak | 16 Av | 768 Bq | 256 Bk | 256 Bv

typedef __bf16 bf16x8 __attribute__((ext_vector_type(8)));
typedef float  f32x4  __attribute__((ext_vector_type(4)));

#define MFMA(a, b, c) __builtin_amdgcn_mfma_f32_16x16x32_bf16((a), (b), (c), 0, 0, 0)

__device__ __forceinline__ void gload_lds16(const void* g, void* l) {
  __builtin_amdgcn_global_load_lds(
      (const __attribute__((address_space(1))) void*)g,
      (__attribute__((address_space(3))) void*)l, 16, 0, 0);
}

// ---- prep: hidden cvt + W_all^T transpose (WoT lives in proj launch) ------

__global__ __launch_bounds__(256) void k_prep(
    const float* __restrict__ hidden,
    const float* __restrict__ WAq, const float* __restrict__ WAk,
    const float* __restrict__ WAv, const float* __restrict__ WBq,
    const float* __restrict__ WBk, const float* __restrict__ WBv,
    __bf16* __restrict__ hid_bf, __bf16* __restrict__ WT) {
  const int bid = blockIdx.x;
  if (bid < 2048) {                       // ---- hidden f32 -> bf16, x8
    const int i = (bid * 256 + threadIdx.x) * 8;
    f32x4 a = *(const f32x4*)(hidden + i);
    f32x4 b = *(const f32x4*)(hidden + i + 4);
    bf16x8 v;
#pragma unroll
    for (int j = 0; j < 4; j++) { v[j] = (__bf16)a[j]; v[4 + j] = (__bf16)b[j]; }
    *(bf16x8*)(hid_bf + i) = v;
  } else {                                // ---- W_all^T [1408][2048]
    const int t = bid - 2048;             // t < 44*64
    const int bc = (t % 44) * 32, bk = (t / 44) * 32;
    __shared__ float tl[32][33];
    const int tx = threadIdx.x & 31, ty = threadIdx.x >> 5;  // ty 0..7
    const int c = bc + tx;
#pragma unroll
    for (int j = 0; j < 32; j += 8) {
      const int k = bk + ty + j;
      float v;
      if (c < 96)        v = WAq[k * 96 + c];
      else if (c < 112)  v = WAk[k * 16 + (c - 96)];
      else if (c < 128)  v = WAv[k * 16 + (c - 112)];
      else if (c < 896)  v = WBq[k * 768 + (c - 128)];
      else if (c < 1152) v = WBk[k * 256 + (c - 896)];
      else               v = WBv[k * 256 + (c - 1152)];
      tl[ty + j][tx] = v;                 // tl[k-local][c-local]
    }
    __syncthreads();
#pragma unroll
    for (int j = 0; j < 32; j += 8)
      WT[(size_t)(bc + ty + j) * HIDN + bk + tx] = (__bf16)tl[tx][ty + j];
  }
}

// ---- fused: proj GEMM split-K=2 (704 blocks) + Wo^T transpose (4096) ------

__global__ __launch_bounds__(256) void k_proj_wo(
    const __bf16* __restrict__ A, const __bf16* __restrict__ BT,
    float* __restrict__ C0, float* __restrict__ C1,
    const float* __restrict__ Wo, __bf16* __restrict__ WoT) {
  __shared__ char smem[49152];            // GEMM: As 32KB | Bs 16KB ; WoT: 4.2KB
  const int bid = blockIdx.x;
  if (bid >= 704) {                       // ---- Wo^T [2048][2048] tile
    const int t = bid - 704;
    const int bn = (t % 64) * 32, bk = (t / 64) * 32;
    float (*tl)[33] = (float(*)[33])smem;
    const int tx = threadIdx.x & 31, ty = threadIdx.x >> 5;
#pragma unroll
    for (int j = 0; j < 32; j += 8)
      tl[ty + j][tx] = Wo[(size_t)(bk + ty + j) * HIDN + bn + tx];
    __syncthreads();
#pragma unroll
    for (int j = 0; j < 32; j += 8)
      WoT[(size_t)(bn + ty + j) * HIDN + bk + tx] = (__bf16)tl[tx][ty + j];
    return;
  }
  // ---- proj GEMM: C[2048][1408] = A[2048][2048] * BT[1408][2048]^T
  const int K = HIDN, N = NCOLS;
  __bf16* As = (__bf16*)smem;             // [4][4096]
  __bf16* Bs = (__bf16*)(smem + 32768);   // [4][2048]
  const int tid = threadIdx.x;
  const int w = tid >> 6, lane = tid & 63;
  const int lhi = lane >> 4, llo = lane & 15;
  const int wr = w >> 1, wc = w & 1;
  const int z = (bid >= 352);
  const int b = bid - z * 352;
  float* C = z ? C1 : C0;
  const int kbase = z * (K >> 1);
  const int sid = (b & 7) * 44 + (b >> 3);   // chunk swizzle (352 % 8 == 0)
  const int brow = (sid / 22) * 128, bcol = (sid % 22) * 64;
  const int rA = lane >> 2, kA = (lane & 3) * 8;
  const int nt = K >> 6;                  // 32 K-steps per half

  f32x4 acc[4][2];
#pragma unroll
  for (int m = 0; m < 4; m++)
#pragma unroll
    for (int n = 0; n < 2; n++) acc[m][n] = (f32x4){0.f, 0.f, 0.f, 0.f};

  auto stage = [&](int t) {               // 3 gload_lds per wave
    const int buf = t & 3;
    const int k0 = kbase + t * 32;
#pragma unroll
    for (int i = 0; i < 2; i++) {
      int seg = w * 2 + i;
      int row = seg * 16 + rA;
      gload_lds16(A + (size_t)(brow + row) * K + k0 + kA,
                  As + buf * 4096 + seg * 512);
    }
    gload_lds16(BT + (size_t)(bcol + w * 16 + rA) * K + k0 + kA,
                Bs + buf * 2048 + w * 512);
  };

  stage(0); stage(1); stage(2);
  asm volatile("s_waitcnt vmcnt(6)" ::: "memory");
  __builtin_amdgcn_s_barrier();

  for (int t = 0; t < nt; t++) {
    if (t + 3 < nt) stage(t + 3);
    const int buf = t & 3;
    bf16x8 af[4], bfr[2];
#pragma unroll
    for (int m = 0; m < 4; m++)
      af[m] = *(const bf16x8*)&As[buf * 4096 + (wr * 64 + m * 16 + llo) * 32 + lhi * 8];
#pragma unroll
    for (int n = 0; n < 2; n++)
      bfr[n] = *(const bf16x8*)&Bs[buf * 2048 + (wc * 32 + n * 16 + llo) * 32 + lhi * 8];
#pragma unroll
    for (int m = 0; m < 4; m++)
#pragma unroll
      for (int n = 0; n < 2; n++) acc[m][n] = MFMA(af[m], bfr[n], acc[m][n]);
    const int rem = nt - 2 - t;
    if (rem >= 2)      asm volatile("s_waitcnt vmcnt(6)" ::: "memory");
    else if (rem == 1) asm volatile("s_waitcnt vmcnt(3)" ::: "memory");
    else               asm volatile("s_waitcnt vmcnt(0)" ::: "memory");
    __builtin_amdgcn_s_barrier();
  }

#pragma unroll
  for (int m = 0; m < 4; m++)
#pragma unroll
    for (int n = 0; n < 2; n++) {
      int r0 = brow + wr * 64 + m * 16 + lhi * 4;
      int c0 = bcol + wc * 32 + n * 16 + llo;
#pragma unroll
      for (int r = 0; r < 4; r++) C[(size_t)(r0 + r) * N + c0] = acc[m][n][r];
    }
}

// ---- out GEMM: 128x128 tile, 8 waves, BK=64, 3-buf depth-2 pipeline -------
// BK 32->64: 16 MFMA/wave between barriers (was 8), barrier count 64->32 —
// the m93->m97 amortization lever. Each K-step stages two lane-linear
// [128][32] half-tiles per operand (same layout/read pattern as BK=32).
// LDS 3 bufs x 16KB x 2 operands = 96KB; grid is 1 block/CU anyway so no
// occupancy cost. WAR: stage(t+2) writes buf (t+2)%3 = (t-1)%3, last read
// by compute(t-1), and is issued only after iter t-1's end barrier (the
// proven k_gemm_bt argument). vmcnt: 4 loads/stage -> (4)/(0) ladder.

__global__ __launch_bounds__(512) void k_gemm_out(const __bf16* __restrict__ A,
                                                  const __bf16* __restrict__ BT,
                                                  float* __restrict__ C) {
  __shared__ __bf16 As[3][8192];  // [buf][half][128 rows][32 k]
  __shared__ __bf16 Bs[3][8192];
  const int K = HIDN, N = HIDN;
  const int tid = threadIdx.x;
  const int w = tid >> 6, lane = tid & 63;
  const int lhi = lane >> 4, llo = lane & 15;
  const int wr = w >> 2, wc = w & 3;

  // 2D region per XCD: 8 rows x 4 cols of 128x128 tiles
  const int id = blockIdx.y * 16 + blockIdx.x;
  const int g = id & 7, kk = id >> 3;     // kk 0..31
  const int rg = g >> 2, cg = g & 3;
  const int brow = (rg * 8 + (kk & 7)) * 128;
  const int bcol = (cg * 4 + (kk >> 3)) * 128;

  const int rA = tid >> 2, kA = (tid & 3) * 8;  // thread -> (row, k-chunk)
  const int nt = K >> 6;                        // 32 steps of 64

  f32x4 acc[4][2];
#pragma unroll
  for (int m = 0; m < 4; m++)
#pragma unroll
    for (int n = 0; n < 2; n++) acc[m][n] = (f32x4){0.f, 0.f, 0.f, 0.f};

  auto stage = [&](int t) {               // 4 gload_lds per wave
    const int buf = t % 3;
    const int k0 = t * 64;
#pragma unroll
    for (int hf = 0; hf < 2; hf++) {
      gload_lds16(A  + (size_t)(brow + rA) * K + k0 + hf * 32 + kA,
                  &As[buf][hf * 4096 + w * 512]);
      gload_lds16(BT + (size_t)(bcol + rA) * K + k0 + hf * 32 + kA,
                  &Bs[buf][hf * 4096 + w * 512]);
    }
  };

  stage(0); stage(1);
  asm volatile("s_waitcnt vmcnt(4)" ::: "memory");   // tile 0 landed
  __builtin_amdgcn_s_barrier();

  for (int t = 0; t < nt; t++) {
    if (t + 2 < nt) stage(t + 2);
    const int buf = t % 3;
#pragma unroll
    for (int hf = 0; hf < 2; hf++) {
      bf16x8 af[4], bfr[2];
#pragma unroll
      for (int m = 0; m < 4; m++)
        af[m] = *(const bf16x8*)&As[buf][hf * 4096 +
                                         (wr * 64 + m * 16 + llo) * 32 + lhi * 8];
#pragma unroll
      for (int n = 0; n < 2; n++)
        bfr[n] = *(const bf16x8*)&Bs[buf][hf * 4096 +
                                          (wc * 32 + n * 16 + llo) * 32 + lhi * 8];
#pragma unroll
      for (int m = 0; m < 4; m++)
#pragma unroll
        for (int n = 0; n < 2; n++) acc[m][n] = MFMA(af[m], bfr[n], acc[m][n]);
    }
    if (t + 2 < nt)      asm volatile("s_waitcnt vmcnt(4)" ::: "memory");
    else if (t + 1 < nt) asm volatile("s_waitcnt vmcnt(0)" ::: "memory");
    __builtin_amdgcn_s_barrier();
  }

#pragma unroll
  for (int m = 0; m < 4; m++)
#pragma unroll
    for (int n = 0; n < 2; n++) {
      int r0 = brow + wr * 64 + m * 16 + lhi * 4;
      int c0 = bcol + wc * 32 + n * 16 + llo;
#pragma unroll
      for (int r = 0; r < 4; r++) C[(size_t)(r0 + r) * N + c0] = acc[m][n][r];
    }
}

// ---- build Q/K/Vp from projection PARTIALS (sum + rope + rank contraction)

__global__ __launch_bounds__(128) void k_build_qkv(const float* __restrict__ P0,
                                                   const float* __restrict__ P1,
                                                   const float* __restrict__ cosT,
                                                   const float* __restrict__ sinT,
                                                   __bf16* __restrict__ Qo,
                                                   __bf16* __restrict__ Ko,
                                                   __bf16* __restrict__ Vto) {
  const int q = blockIdx.x, d = threadIdx.x;  // 128 threads
  __shared__ float Ash[128];                  // Aq(96) | Ak(16) | Av(16)
  const float* r0 = P0 + (size_t)q * NCOLS;
  const float* r1 = P1 + (size_t)q * NCOLS;
  auto rd = [&](int i) { return r0[i] + r1[i]; };  // merge split-K halves
  Ash[d] = rd(d);
  __syncthreads();
  const int m2 = (d >> 1) * 2;
  const bool odd = d & 1;
  const float c = cosT[q * 64 + (d >> 1)];
  const float s = sinT[q * 64 + (d >> 1)];

  float qacc[16];
#pragma unroll
  for (int h = 0; h < 16; h++) qacc[h] = 0.f;
#pragma unroll
  for (int r = 0; r < 6; r++) {
    float xe = rd(128 + r * 128 + m2);
    float xo = rd(128 + r * 128 + m2 + 1);
    float br = odd ? (xe * s + xo * c) : (xe * c - xo * s);
#pragma unroll
    for (int h = 0; h < 16; h++) qacc[h] += Ash[h * 6 + r] * br;
  }
#pragma unroll
  for (int h = 0; h < 16; h++)
    Qo[((size_t)h * SEQ + q) * DH + d] = (__bf16)(qacc[h] * 0.08838834764831845f);

  float kacc[8];
#pragma unroll
  for (int g = 0; g < 8; g++) kacc[g] = 0.f;
#pragma unroll
  for (int ss = 0; ss < 2; ss++) {
    float xe = rd(896 + ss * 128 + m2);
    float xo = rd(896 + ss * 128 + m2 + 1);
    float bs = odd ? (xe * s + xo * c) : (xe * c - xo * s);
#pragma unroll
    for (int g = 0; g < 8; g++) kacc[g] += Ash[96 + g * 2 + ss] * bs;
  }
#pragma unroll
  for (int g = 0; g < 8; g++)
    Ko[((size_t)g * SEQ + q) * DH + d] = (__bf16)kacc[g];

  float vacc[8];
#pragma unroll
  for (int g = 0; g < 8; g++) vacc[g] = 0.f;
#pragma unroll
  for (int u = 0; u < 2; u++) {
    float vu = rd(1152 + u * 128 + d);
#pragma unroll
    for (int g = 0; g < 8; g++) vacc[g] += Ash[112 + g * 2 + u] * vu;
  }
  // pi(k) = ((k&15)>>2)*8 + (k&3) + ((k&16)>>2)
  const int qp = (q & ~31) | (((q & 15) >> 2) * 8 + (q & 3) + ((q & 16) >> 2));
#pragma unroll
  for (int g = 0; g < 8; g++)
    Vto[((size_t)g * DH + d) * SEQ + qp] = (__bf16)vacc[g];
}

// ---- flash attention (R19 — proven best; frozen control) ------------------
// split-KV parts=2, XCD-affine, 2-buffer staged (vmcnt(4) counted), swapped
// QK^T + in-register P, key-permuted V, setprio around MFMA clusters.

__global__ __launch_bounds__(256) void k_attn(const __bf16* __restrict__ Q,
                                              const __bf16* __restrict__ Kc,
                                              const __bf16* __restrict__ Vt,
                                              float* __restrict__ AOf0,
                                              float* __restrict__ AOf1,
                                              float* __restrict__ Ls) {
  const int raw = blockIdx.x;          // 0..1023
  const int g = raw & 7;               // XCD affinity
  const int j = raw >> 3;              // 0..127
  const int bqi = 31 - (j >> 2);       // heavy-first per XCD stripe
  const int hh = (j >> 1) & 1;
  const int p = j & 1;
  const int h = g * 2 + hh;
  const int w = threadIdx.x >> 6, lane = threadIdx.x & 63;
  const int lhi = lane >> 4, llo = lane & 15;
  const int q0 = bqi * 64 + w * 16;
  const int t0 = p * (bqi + 1), t1 = t0 + bqi + 1;  // half the causal tiles

  __shared__ __bf16 KVs[2][8192];    // 8KB K (32x128 swz) | 8KB V (128x32 perm)

  const __bf16* Qh = Q  + (size_t)h * SEQ * DH;
  const __bf16* Kg = Kc + (size_t)g * SEQ * DH;
  const __bf16* Vg = Vt + (size_t)g * DH * SEQ;
  float* AOc = p ? AOf1 : AOf0;

  bf16x8 aq[4];
#pragma unroll
  for (int c = 0; c < 4; c++)
    aq[c] = *(const bf16x8*)&Qh[(size_t)(q0 + llo) * DH + c * 32 + lhi * 8];

  f32x4 oacc[8];
  float lsum = 0.f;
#pragma unroll
  for (int n = 0; n < 8; n++) oacc[n] = (f32x4){0.f, 0.f, 0.f, 0.f};

  // PV B-frag read: one b128 at kslots lhi*8..+7, row d = n*16+llo.
  const int vb = llo * 64 + ((lhi ^ ((llo >> 1) & 3)) << 4);

  auto stage = [&](int kb, int buf) {
    __bf16* L = KVs[buf];
    if (w < 2) {
#pragma unroll
      for (int u = 0; u < 4; u++) {
        int c = w * 256 + u * 64 + lane;
        int row = c >> 4, jj = c & 15;
        gload_lds16(Kg + (size_t)(kb + row) * DH + ((jj ^ (row & 7)) * 8),
                    L + (w * 256 + u * 64) * 8);
      }
    } else {
#pragma unroll
      for (int u = 0; u < 4; u++) {
        int c = (w - 2) * 256 + u * 64 + lane;
        int d = c >> 2, jj = c & 3;
        gload_lds16(Vg + (size_t)d * SEQ + kb + ((jj ^ ((d >> 1) & 3)) * 8),
                    L + 4096 + ((w - 2) * 256 + u * 64) * 8);
      }
    }
  };

  stage(t0 * 32, t0 & 1);
  for (int t = t0; t < t1; t++) {
    const int kb = t * 32;
    const int buf = t & 1;
    if (t + 1 < t1) {
      stage(kb + 32, buf ^ 1);
      asm volatile("s_waitcnt vmcnt(4)" ::: "memory");  // cur tile staged
    } else {
      asm volatile("s_waitcnt vmcnt(0)" ::: "memory");
    }
    __builtin_amdgcn_s_barrier();
    if (kb <= q0 + 15) {   // wave-uniform skip of fully-masked tiles
      const char* Kl = (const char*)KVs[buf];
      const char* Vl = (const char*)(KVs[buf] + 4096);
      f32x4 s0 = {0.f, 0.f, 0.f, 0.f}, s1 = {0.f, 0.f, 0.f, 0.f};
      __builtin_amdgcn_s_setprio(1);
#pragma unroll
      for (int c = 0; c < 4; c++) {
        const int row0 = llo, row1 = 16 + llo;
        bf16x8 k0 = *(const bf16x8*)(Kl + row0 * 256 +
                                     ((c * 64 + lhi * 16) ^ ((row0 & 7) << 4)));
        bf16x8 k1 = *(const bf16x8*)(Kl + row1 * 256 +
                                     ((c * 64 + lhi * 16) ^ ((row1 & 7) << 4)));
        s0 = MFMA(k0, aq[c], s0);   // swapped: S^T[key][q]
        s1 = MFMA(k1, aq[c], s1);
      }
      __builtin_amdgcn_s_setprio(0);
      float e[8];
#pragma unroll
      for (int r = 0; r < 4; r++) {
        float a0 = exp2f(s0[r] * 0.057707802f);
        float a1 = exp2f(s1[r] * 0.057707802f);
        e[r]     = exp2f(72.134752f - 144.269504f * __builtin_amdgcn_rcpf(a0 + 1.f));
        e[4 + r] = exp2f(72.134752f - 144.269504f * __builtin_amdgcn_rcpf(a1 + 1.f));
      }
      if (kb + 31 > q0) {          // diagonal tile only: causal mask
        const int qrow = q0 + llo;
#pragma unroll
        for (int r = 0; r < 4; r++) {
          if (kb + lhi * 4 + r > qrow)      e[r] = 0.f;
          if (kb + 16 + lhi * 4 + r > qrow) e[4 + r] = 0.f;
        }
      }
#pragma unroll
      for (int r = 0; r < 4; r++) lsum += e[r] + e[4 + r];
      union { bf16x8 v8; unsigned u[4]; } pu;
      asm("v_cvt_pk_bf16_f32 %0, %1, %2" : "=v"(pu.u[0]) : "v"(e[0]), "v"(e[1]));
      asm("v_cvt_pk_bf16_f32 %0, %1, %2" : "=v"(pu.u[1]) : "v"(e[2]), "v"(e[3]));
      asm("v_cvt_pk_bf16_f32 %0, %1, %2" : "=v"(pu.u[2]) : "v"(e[4]), "v"(e[5]));
      asm("v_cvt_pk_bf16_f32 %0, %1, %2" : "=v"(pu.u[3]) : "v"(e[6]), "v"(e[7]));
      __builtin_amdgcn_s_setprio(1);
#pragma unroll
      for (int n = 0; n < 8; n++) {
        bf16x8 vf = *(const bf16x8*)(Vl + vb + n * 1024);
        oacc[n] = MFMA(pu.v8, vf, oacc[n]);
      }
      __builtin_amdgcn_s_setprio(0);
    }
    asm volatile("" ::: "memory");
    __builtin_amdgcn_s_barrier();
  }

  float tsum = lsum;
  tsum += __shfl_xor(tsum, 16);
  tsum += __shfl_xor(tsum, 32);
  if (lhi == 0) Ls[((size_t)p * NHEAD + h) * SEQ + q0 + llo] = tsum;
#pragma unroll
  for (int r = 0; r < 4; r++) {
    const int qrow = q0 + lhi * 4 + r;
#pragma unroll
    for (int n = 0; n < 8; n++)
      AOc[(size_t)qrow * HIDN + h * DH + n * 16 + llo] = oacc[n][r];
  }
}

// ---- merge split-KV partials, normalize, cast to bf16 ---------------------

__global__ __launch_bounds__(256) void k_norm(const float* __restrict__ A0,
                                              const float* __restrict__ A1,
                                              const float* __restrict__ Ls,
                                              __bf16* __restrict__ AO) {
  const int i = (blockIdx.x * 256 + threadIdx.x) * 4;  // 4M elems, f32x4
  const int q = i >> 11, h = (i & 2047) >> 7;
  const float inv = 1.f / (Ls[h * SEQ + q] + Ls[(NHEAD + h) * SEQ + q]);
  f32x4 a = *(const f32x4*)(A0 + i);
  f32x4 b = *(const f32x4*)(A1 + i);
#pragma unroll
  for (int j = 0; j < 4; j++) AO[i + j] = (__bf16)((a[j] + b[j]) * inv);
}

// ---------------------------------------------------------------------------

extern "C" void kernel_launch(void* const* d_in, const int* in_sizes, int n_in,
                              void* d_out, int out_size, void* d_ws, size_t ws_size,
                              hipStream_t stream) {
  const float* hidden = (const float*)d_in[0];
  const float* cosT   = (const float*)d_in[1];
  const float* sinT   = (const float*)d_in[2];
  // d_in[3] = mask (pure causal, computed analytically), d_in[4] = arange (unused)
  const float* WAq = (const float*)d_in[5];
  const float* WAk = (const float*)d_in[6];
  const float* WAv = (const float*)d_in[7];
  const float* WBq = (const float*)d_in[8];
  const float* WBk = (const float*)d_in[9];
  const float* WBv = (const float*)d_in[10];
  const float* Wo  = (const float*)d_in[11];
  float* out = (float*)d_out;

  // Workspace layout (lifetime-aliased), ~67.9 MB:
  //   [0)          hid_bf (8.39M)  -> AOf0 (16.78M) after proj is done
  //   [8388608)    WallT  (5.77M)      (overlaid by AOf0)
  //   [14155776)   Pp0    (11.53M)     (first 2.6M overlaid by AOf0; dead
  //                                     after build_qkv)
  //   [25690112)   WoT    (8.39M)      (live until final GEMM)
  //   [34078720)   Qb     (8.39M)  -> AO bf16 after attn is done
  //   [42467328)   Kb     (4.19M)
  //   [46661632)   Vt     (4.19M)
  //   [50855936)   Pp1    (11.53M) -> AOf1 (16.78M) after build_qkv is done
  //   [67633152)   Ls     (0.26M)
  char* ws = (char*)d_ws;
  __bf16* hid_bf = (__bf16*)(ws);
  __bf16* WallT  = (__bf16*)(ws + 8388608);
  float*  Pp0    = (float*)(ws + 14155776);
  __bf16* WoT    = (__bf16*)(ws + 25690112);
  __bf16* Qb     = (__bf16*)(ws + 34078720);
  __bf16* Kb     = (__bf16*)(ws + 42467328);
  __bf16* Vt     = (__bf16*)(ws + 46661632);
  float*  Pp1    = (float*)(ws + 50855936);
  float*  AOf0   = (float*)(ws);
  float*  AOf1   = (float*)(ws + 50855936);
  float*  Ls     = (float*)(ws + 67633152);
  __bf16* AO     = (__bf16*)(ws + 34078720);  // aliases Qb (dead after attn)

  // prep: 2048 cvt blocks + 44*64 wall-transpose
  k_prep<<<2048 + 44 * 64, 256, 0, stream>>>(
      hidden, WAq, WAk, WAv, WBq, WBk, WBv, hid_bf, WallT);
  // proj GEMM split-K=2 (704 blocks) + WoT transpose (4096 blocks) fused
  k_proj_wo<<<704 + 4096, 256, 0, stream>>>(hid_bf, WallT, Pp0, Pp1, Wo, WoT);
  k_build_qkv<<<SEQ, 128, 0, stream>>>(Pp0, Pp1, cosT, sinT, Qb, Kb, Vt);
  k_attn<<<1024, 256, 0, stream>>>(Qb, Kb, Vt, AOf0, AOf1, Ls);
  k_norm<<<(SEQ * HIDN / 4) / 256, 256, 0, stream>>>(AOf0, AOf1, Ls, AO);
  k_gemm_out<<<dim3(16, 16), 512, 0, stream>>>(AO, WoT, out);
}

// Round 21
// 141.334 us; speedup vs baseline: 1.1230x; 1.0012x over previous
//
#include <hip/hip_runtime.h>

// ---------------------------------------------------------------------------
// TPA attention, factorized to GQA flash attention.
// B=1, S=2048, HID=2048, H=16, KVH=8, D=128, QR=6, KR=2, VR=2
// ---------------------------------------------------------------------------

constexpr int SEQ   = 2048;
constexpr int HIDN  = 2048;
constexpr int NHEAD = 16;
constexpr int NKVH  = 8;
constexpr int DH    = 128;
constexpr int NCOLS = 1408;   // 96 Aq | 16 Ak | 16 Av | 768 Bq | 256 Bk | 256 Bv

typedef __bf16 bf16x8 __attribute__((ext_vector_type(8)));
typedef float  f32x4  __attribute__((ext_vector_type(4)));

#define MFMA(a, b, c) __builtin_amdgcn_mfma_f32_16x16x32_bf16((a), (b), (c), 0, 0, 0)

__device__ __forceinline__ void gload_lds16(const void* g, void* l) {
  __builtin_amdgcn_global_load_lds(
      (const __attribute__((address_space(1))) void*)g,
      (__attribute__((address_space(3))) void*)l, 16, 0, 0);
}

// ---- prep: hidden cvt + W_all^T transpose (WoT lives in proj launch) ------

__global__ __launch_bounds__(256) void k_prep(
    const float* __restrict__ hidden,
    const float* __restrict__ WAq, const float* __restrict__ WAk,
    const float* __restrict__ WAv, const float* __restrict__ WBq,
    const float* __restrict__ WBk, const float* __restrict__ WBv,
    __bf16* __restrict__ hid_bf, __bf16* __restrict__ WT) {
  const int bid = blockIdx.x;
  if (bid < 2048) {                       // ---- hidden f32 -> bf16, x8
    const int i = (bid * 256 + threadIdx.x) * 8;
    f32x4 a = *(const f32x4*)(hidden + i);
    f32x4 b = *(const f32x4*)(hidden + i + 4);
    bf16x8 v;
#pragma unroll
    for (int j = 0; j < 4; j++) { v[j] = (__bf16)a[j]; v[4 + j] = (__bf16)b[j]; }
    *(bf16x8*)(hid_bf + i) = v;
  } else {                                // ---- W_all^T [1408][2048]
    const int t = bid - 2048;             // t < 44*64
    const int bc = (t % 44) * 32, bk = (t / 44) * 32;
    __shared__ float tl[32][33];
    const int tx = threadIdx.x & 31, ty = threadIdx.x >> 5;  // ty 0..7
    const int c = bc + tx;
#pragma unroll
    for (int j = 0; j < 32; j += 8) {
      const int k = bk + ty + j;
      float v;
      if (c < 96)        v = WAq[k * 96 + c];
      else if (c < 112)  v = WAk[k * 16 + (c - 96)];
      else if (c < 128)  v = WAv[k * 16 + (c - 112)];
      else if (c < 896)  v = WBq[k * 768 + (c - 128)];
      else if (c < 1152) v = WBk[k * 256 + (c - 896)];
      else               v = WBv[k * 256 + (c - 1152)];
      tl[ty + j][tx] = v;                 // tl[k-local][c-local]
    }
    __syncthreads();
#pragma unroll
    for (int j = 0; j < 32; j += 8)
      WT[(size_t)(bc + ty + j) * HIDN + bk + tx] = (__bf16)tl[tx][ty + j];
  }
}

// ---- fused: proj GEMM split-K=2 (704 blocks) + Wo^T transpose (4096) ------
// NEW: proj GEMM BK 32->64 (R20's proven amortization lever): 16 MFMA/wave
// between barriers (was 8), 16 K-steps per split-K half (was 32). 3 LDS
// buffers x (A 16KB + B 8KB) = 72KB -> 2 blocks/CU; the 4096 WoT tiles
// backfill the tail round. Stage = 6 gload_lds/wave; vmcnt 6/0 ladder.
// WAR: stage(t+2) writes buf (t-1)%3, separated from compute(t-1) by the
// end-of-iter-(t-1) barrier (proven 3-buf argument from k_gemm_out).

__global__ __launch_bounds__(256) void k_proj_wo(
    const __bf16* __restrict__ A, const __bf16* __restrict__ BT,
    float* __restrict__ C0, float* __restrict__ C1,
    const float* __restrict__ Wo, __bf16* __restrict__ WoT) {
  __shared__ char smem[73728];            // GEMM: As 48KB | Bs 24KB ; WoT: 4.2KB
  const int bid = blockIdx.x;
  if (bid >= 704) {                       // ---- Wo^T [2048][2048] tile
    const int t = bid - 704;
    const int bn = (t % 64) * 32, bk = (t / 64) * 32;
    float (*tl)[33] = (float(*)[33])smem;
    const int tx = threadIdx.x & 31, ty = threadIdx.x >> 5;
#pragma unroll
    for (int j = 0; j < 32; j += 8)
      tl[ty + j][tx] = Wo[(size_t)(bk + ty + j) * HIDN + bn + tx];
    __syncthreads();
#pragma unroll
    for (int j = 0; j < 32; j += 8)
      WoT[(size_t)(bn + ty + j) * HIDN + bk + tx] = (__bf16)tl[tx][ty + j];
    return;
  }
  // ---- proj GEMM: C[2048][1408] = A[2048][2048] * BT[1408][2048]^T
  const int K = HIDN, N = NCOLS;
  __bf16* As = (__bf16*)smem;             // [3][2 halves][128 rows][32 k]
  __bf16* Bs = (__bf16*)(smem + 49152);   // [3][2 halves][64 cols][32 k]
  const int tid = threadIdx.x;
  const int w = tid >> 6, lane = tid & 63;
  const int lhi = lane >> 4, llo = lane & 15;
  const int wr = w >> 1, wc = w & 1;
  const int z = (bid >= 352);
  const int b = bid - z * 352;
  float* C = z ? C1 : C0;
  const int kbase = z * (K >> 1);
  const int sid = (b & 7) * 44 + (b >> 3);   // chunk swizzle (352 % 8 == 0)
  const int brow = (sid / 22) * 128, bcol = (sid % 22) * 64;
  const int rA = lane >> 2, kA = (lane & 3) * 8;
  const int nt = K >> 7;                  // 16 K-steps of 64 per half

  f32x4 acc[4][2];
#pragma unroll
  for (int m = 0; m < 4; m++)
#pragma unroll
    for (int n = 0; n < 2; n++) acc[m][n] = (f32x4){0.f, 0.f, 0.f, 0.f};

  auto stage = [&](int t) {               // 6 gload_lds per wave
    const int buf = t % 3;
    const int k0 = kbase + t * 64;
#pragma unroll
    for (int hf = 0; hf < 2; hf++) {
#pragma unroll
      for (int i = 0; i < 2; i++) {
        int seg = w * 2 + i;
        int row = seg * 16 + rA;
        gload_lds16(A + (size_t)(brow + row) * K + k0 + hf * 32 + kA,
                    As + buf * 8192 + hf * 4096 + seg * 512);
      }
      gload_lds16(BT + (size_t)(bcol + w * 16 + rA) * K + k0 + hf * 32 + kA,
                  Bs + buf * 4096 + hf * 2048 + w * 512);
    }
  };

  stage(0); stage(1);
  asm volatile("s_waitcnt vmcnt(6)" ::: "memory");   // tile 0 landed
  __builtin_amdgcn_s_barrier();

  for (int t = 0; t < nt; t++) {
    if (t + 2 < nt) stage(t + 2);
    const int buf = t % 3;
#pragma unroll
    for (int hf = 0; hf < 2; hf++) {
      bf16x8 af[4], bfr[2];
#pragma unroll
      for (int m = 0; m < 4; m++)
        af[m] = *(const bf16x8*)&As[buf * 8192 + hf * 4096 +
                                    (wr * 64 + m * 16 + llo) * 32 + lhi * 8];
#pragma unroll
      for (int n = 0; n < 2; n++)
        bfr[n] = *(const bf16x8*)&Bs[buf * 4096 + hf * 2048 +
                                     (wc * 32 + n * 16 + llo) * 32 + lhi * 8];
#pragma unroll
      for (int m = 0; m < 4; m++)
#pragma unroll
        for (int n = 0; n < 2; n++) acc[m][n] = MFMA(af[m], bfr[n], acc[m][n]);
    }
    if (t + 2 < nt)      asm volatile("s_waitcnt vmcnt(6)" ::: "memory");
    else if (t + 1 < nt) asm volatile("s_waitcnt vmcnt(0)" ::: "memory");
    __builtin_amdgcn_s_barrier();
  }

#pragma unroll
  for (int m = 0; m < 4; m++)
#pragma unroll
    for (int n = 0; n < 2; n++) {
      int r0 = brow + wr * 64 + m * 16 + lhi * 4;
      int c0 = bcol + wc * 32 + n * 16 + llo;
#pragma unroll
      for (int r = 0; r < 4; r++) C[(size_t)(r0 + r) * N + c0] = acc[m][n][r];
    }
}

// ---- out GEMM: 128x128 tile, 8 waves, BK=64, 3-buf depth-2 pipeline -------
// (R20 version — proven −6.7us.)

__global__ __launch_bounds__(512) void k_gemm_out(const __bf16* __restrict__ A,
                                                  const __bf16* __restrict__ BT,
                                                  float* __restrict__ C) {
  __shared__ __bf16 As[3][8192];  // [buf][half][128 rows][32 k]
  __shared__ __bf16 Bs[3][8192];
  const int K = HIDN, N = HIDN;
  const int tid = threadIdx.x;
  const int w = tid >> 6, lane = tid & 63;
  const int lhi = lane >> 4, llo = lane & 15;
  const int wr = w >> 2, wc = w & 3;

  // 2D region per XCD: 8 rows x 4 cols of 128x128 tiles
  const int id = blockIdx.y * 16 + blockIdx.x;
  const int g = id & 7, kk = id >> 3;     // kk 0..31
  const int rg = g >> 2, cg = g & 3;
  const int brow = (rg * 8 + (kk & 7)) * 128;
  const int bcol = (cg * 4 + (kk >> 3)) * 128;

  const int rA = tid >> 2, kA = (tid & 3) * 8;  // thread -> (row, k-chunk)
  const int nt = K >> 6;                        // 32 steps of 64

  f32x4 acc[4][2];
#pragma unroll
  for (int m = 0; m < 4; m++)
#pragma unroll
    for (int n = 0; n < 2; n++) acc[m][n] = (f32x4){0.f, 0.f, 0.f, 0.f};

  auto stage = [&](int t) {               // 4 gload_lds per wave
    const int buf = t % 3;
    const int k0 = t * 64;
#pragma unroll
    for (int hf = 0; hf < 2; hf++) {
      gload_lds16(A  + (size_t)(brow + rA) * K + k0 + hf * 32 + kA,
                  &As[buf][hf * 4096 + w * 512]);
      gload_lds16(BT + (size_t)(bcol + rA) * K + k0 + hf * 32 + kA,
                  &Bs[buf][hf * 4096 + w * 512]);
    }
  };

  stage(0); stage(1);
  asm volatile("s_waitcnt vmcnt(4)" ::: "memory");   // tile 0 landed
  __builtin_amdgcn_s_barrier();

  for (int t = 0; t < nt; t++) {
    if (t + 2 < nt) stage(t + 2);
    const int buf = t % 3;
#pragma unroll
    for (int hf = 0; hf < 2; hf++) {
      bf16x8 af[4], bfr[2];
#pragma unroll
      for (int m = 0; m < 4; m++)
        af[m] = *(const bf16x8*)&As[buf][hf * 4096 +
                                         (wr * 64 + m * 16 + llo) * 32 + lhi * 8];
#pragma unroll
      for (int n = 0; n < 2; n++)
        bfr[n] = *(const bf16x8*)&Bs[buf][hf * 4096 +
                                          (wc * 32 + n * 16 + llo) * 32 + lhi * 8];
#pragma unroll
      for (int m = 0; m < 4; m++)
#pragma unroll
        for (int n = 0; n < 2; n++) acc[m][n] = MFMA(af[m], bfr[n], acc[m][n]);
    }
    if (t + 2 < nt)      asm volatile("s_waitcnt vmcnt(4)" ::: "memory");
    else if (t + 1 < nt) asm volatile("s_waitcnt vmcnt(0)" ::: "memory");
    __builtin_amdgcn_s_barrier();
  }

#pragma unroll
  for (int m = 0; m < 4; m++)
#pragma unroll
    for (int n = 0; n < 2; n++) {
      int r0 = brow + wr * 64 + m * 16 + lhi * 4;
      int c0 = bcol + wc * 32 + n * 16 + llo;
#pragma unroll
      for (int r = 0; r < 4; r++) C[(size_t)(r0 + r) * N + c0] = acc[m][n][r];
    }
}

// ---- build Q/K/Vp from projection PARTIALS (sum + rope + rank contraction)

__global__ __launch_bounds__(128) void k_build_qkv(const float* __restrict__ P0,
                                                   const float* __restrict__ P1,
                                                   const float* __restrict__ cosT,
                                                   const float* __restrict__ sinT,
                                                   __bf16* __restrict__ Qo,
                                                   __bf16* __restrict__ Ko,
                                                   __bf16* __restrict__ Vto) {
  const int q = blockIdx.x, d = threadIdx.x;  // 128 threads
  __shared__ float Ash[128];                  // Aq(96) | Ak(16) | Av(16)
  const float* r0 = P0 + (size_t)q * NCOLS;
  const float* r1 = P1 + (size_t)q * NCOLS;
  auto rd = [&](int i) { return r0[i] + r1[i]; };  // merge split-K halves
  Ash[d] = rd(d);
  __syncthreads();
  const int m2 = (d >> 1) * 2;
  const bool odd = d & 1;
  const float c = cosT[q * 64 + (d >> 1)];
  const float s = sinT[q * 64 + (d >> 1)];

  float qacc[16];
#pragma unroll
  for (int h = 0; h < 16; h++) qacc[h] = 0.f;
#pragma unroll
  for (int r = 0; r < 6; r++) {
    float xe = rd(128 + r * 128 + m2);
    float xo = rd(128 + r * 128 + m2 + 1);
    float br = odd ? (xe * s + xo * c) : (xe * c - xo * s);
#pragma unroll
    for (int h = 0; h < 16; h++) qacc[h] += Ash[h * 6 + r] * br;
  }
#pragma unroll
  for (int h = 0; h < 16; h++)
    Qo[((size_t)h * SEQ + q) * DH + d] = (__bf16)(qacc[h] * 0.08838834764831845f);

  float kacc[8];
#pragma unroll
  for (int g = 0; g < 8; g++) kacc[g] = 0.f;
#pragma unroll
  for (int ss = 0; ss < 2; ss++) {
    float xe = rd(896 + ss * 128 + m2);
    float xo = rd(896 + ss * 128 + m2 + 1);
    float bs = odd ? (xe * s + xo * c) : (xe * c - xo * s);
#pragma unroll
    for (int g = 0; g < 8; g++) kacc[g] += Ash[96 + g * 2 + ss] * bs;
  }
#pragma unroll
  for (int g = 0; g < 8; g++)
    Ko[((size_t)g * SEQ + q) * DH + d] = (__bf16)kacc[g];

  float vacc[8];
#pragma unroll
  for (int g = 0; g < 8; g++) vacc[g] = 0.f;
#pragma unroll
  for (int u = 0; u < 2; u++) {
    float vu = rd(1152 + u * 128 + d);
#pragma unroll
    for (int g = 0; g < 8; g++) vacc[g] += Ash[112 + g * 2 + u] * vu;
  }
  // pi(k) = ((k&15)>>2)*8 + (k&3) + ((k&16)>>2)
  const int qp = (q & ~31) | (((q & 15) >> 2) * 8 + (q & 3) + ((q & 16) >> 2));
#pragma unroll
  for (int g = 0; g < 8; g++)
    Vto[((size_t)g * DH + d) * SEQ + qp] = (__bf16)vacc[g];
}

// ---- flash attention (R19 — proven best; frozen control) ------------------
// split-KV parts=2, XCD-affine, 2-buffer staged (vmcnt(4) counted), swapped
// QK^T + in-register P, key-permuted V, setprio around MFMA clusters.

__global__ __launch_bounds__(256) void k_attn(const __bf16* __restrict__ Q,
                                              const __bf16* __restrict__ Kc,
                                              const __bf16* __restrict__ Vt,
                                              float* __restrict__ AOf0,
                                              float* __restrict__ AOf1,
                                              float* __restrict__ Ls) {
  const int raw = blockIdx.x;          // 0..1023
  const int g = raw & 7;               // XCD affinity
  const int j = raw >> 3;              // 0..127
  const int bqi = 31 - (j >> 2);       // heavy-first per XCD stripe
  const int hh = (j >> 1) & 1;
  const int p = j & 1;
  const int h = g * 2 + hh;
  const int w = threadIdx.x >> 6, lane = threadIdx.x & 63;
  const int lhi = lane >> 4, llo = lane & 15;
  const int q0 = bqi * 64 + w * 16;
  const int t0 = p * (bqi + 1), t1 = t0 + bqi + 1;  // half the causal tiles

  __shared__ __bf16 KVs[2][8192];    // 8KB K (32x128 swz) | 8KB V (128x32 perm)

  const __bf16* Qh = Q  + (size_t)h * SEQ * DH;
  const __bf16* Kg = Kc + (size_t)g * SEQ * DH;
  const __bf16* Vg = Vt + (size_t)g * DH * SEQ;
  float* AOc = p ? AOf1 : AOf0;

  bf16x8 aq[4];
#pragma unroll
  for (int c = 0; c < 4; c++)
    aq[c] = *(const bf16x8*)&Qh[(size_t)(q0 + llo) * DH + c * 32 + lhi * 8];

  f32x4 oacc[8];
  float lsum = 0.f;
#pragma unroll
  for (int n = 0; n < 8; n++) oacc[n] = (f32x4){0.f, 0.f, 0.f, 0.f};

  // PV B-frag read: one b128 at kslots lhi*8..+7, row d = n*16+llo.
  const int vb = llo * 64 + ((lhi ^ ((llo >> 1) & 3)) << 4);

  auto stage = [&](int kb, int buf) {
    __bf16* L = KVs[buf];
    if (w < 2) {
#pragma unroll
      for (int u = 0; u < 4; u++) {
        int c = w * 256 + u * 64 + lane;
        int row = c >> 4, jj = c & 15;
        gload_lds16(Kg + (size_t)(kb + row) * DH + ((jj ^ (row & 7)) * 8),
                    L + (w * 256 + u * 64) * 8);
      }
    } else {
#pragma unroll
      for (int u = 0; u < 4; u++) {
        int c = (w - 2) * 256 + u * 64 + lane;
        int d = c >> 2, jj = c & 3;
        gload_lds16(Vg + (size_t)d * SEQ + kb + ((jj ^ ((d >> 1) & 3)) * 8),
                    L + 4096 + ((w - 2) * 256 + u * 64) * 8);
      }
    }
  };

  stage(t0 * 32, t0 & 1);
  for (int t = t0; t < t1; t++) {
    const int kb = t * 32;
    const int buf = t & 1;
    if (t + 1 < t1) {
      stage(kb + 32, buf ^ 1);
      asm volatile("s_waitcnt vmcnt(4)" ::: "memory");  // cur tile staged
    } else {
      asm volatile("s_waitcnt vmcnt(0)" ::: "memory");
    }
    __builtin_amdgcn_s_barrier();
    if (kb <= q0 + 15) {   // wave-uniform skip of fully-masked tiles
      const char* Kl = (const char*)KVs[buf];
      const char* Vl = (const char*)(KVs[buf] + 4096);
      f32x4 s0 = {0.f, 0.f, 0.f, 0.f}, s1 = {0.f, 0.f, 0.f, 0.f};
      __builtin_amdgcn_s_setprio(1);
#pragma unroll
      for (int c = 0; c < 4; c++) {
        const int row0 = llo, row1 = 16 + llo;
        bf16x8 k0 = *(const bf16x8*)(Kl + row0 * 256 +
                                     ((c * 64 + lhi * 16) ^ ((row0 & 7) << 4)));
        bf16x8 k1 = *(const bf16x8*)(Kl + row1 * 256 +
                                     ((c * 64 + lhi * 16) ^ ((row1 & 7) << 4)));
        s0 = MFMA(k0, aq[c], s0);   // swapped: S^T[key][q]
        s1 = MFMA(k1, aq[c], s1);
      }
      __builtin_amdgcn_s_setprio(0);
      float e[8];
#pragma unroll
      for (int r = 0; r < 4; r++) {
        float a0 = exp2f(s0[r] * 0.057707802f);
        float a1 = exp2f(s1[r] * 0.057707802f);
        e[r]     = exp2f(72.134752f - 144.269504f * __builtin_amdgcn_rcpf(a0 + 1.f));
        e[4 + r] = exp2f(72.134752f - 144.269504f * __builtin_amdgcn_rcpf(a1 + 1.f));
      }
      if (kb + 31 > q0) {          // diagonal tile only: causal mask
        const int qrow = q0 + llo;
#pragma unroll
        for (int r = 0; r < 4; r++) {
          if (kb + lhi * 4 + r > qrow)      e[r] = 0.f;
          if (kb + 16 + lhi * 4 + r > qrow) e[4 + r] = 0.f;
        }
      }
#pragma unroll
      for (int r = 0; r < 4; r++) lsum += e[r] + e[4 + r];
      union { bf16x8 v8; unsigned u[4]; } pu;
      asm("v_cvt_pk_bf16_f32 %0, %1, %2" : "=v"(pu.u[0]) : "v"(e[0]), "v"(e[1]));
      asm("v_cvt_pk_bf16_f32 %0, %1, %2" : "=v"(pu.u[1]) : "v"(e[2]), "v"(e[3]));
      asm("v_cvt_pk_bf16_f32 %0, %1, %2" : "=v"(pu.u[2]) : "v"(e[4]), "v"(e[5]));
      asm("v_cvt_pk_bf16_f32 %0, %1, %2" : "=v"(pu.u[3]) : "v"(e[6]), "v"(e[7]));
      __builtin_amdgcn_s_setprio(1);
#pragma unroll
      for (int n = 0; n < 8; n++) {
        bf16x8 vf = *(const bf16x8*)(Vl + vb + n * 1024);
        oacc[n] = MFMA(pu.v8, vf, oacc[n]);
      }
      __builtin_amdgcn_s_setprio(0);
    }
    asm volatile("" ::: "memory");
    __builtin_amdgcn_s_barrier();
  }

  float tsum = lsum;
  tsum += __shfl_xor(tsum, 16);
  tsum += __shfl_xor(tsum, 32);
  if (lhi == 0) Ls[((size_t)p * NHEAD + h) * SEQ + q0 + llo] = tsum;
#pragma unroll
  for (int r = 0; r < 4; r++) {
    const int qrow = q0 + lhi * 4 + r;
#pragma unroll
    for (int n = 0; n < 8; n++)
      AOc[(size_t)qrow * HIDN + h * DH + n * 16 + llo] = oacc[n][r];
  }
}

// ---- merge split-KV partials, normalize, cast to bf16 ---------------------

__global__ __launch_bounds__(256) void k_norm(const float* __restrict__ A0,
                                              const float* __restrict__ A1,
                                              const float* __restrict__ Ls,
                                              __bf16* __restrict__ AO) {
  const int i = (blockIdx.x * 256 + threadIdx.x) * 4;  // 4M elems, f32x4
  const int q = i >> 11, h = (i & 2047) >> 7;
  const float inv = 1.f / (Ls[h * SEQ + q] + Ls[(NHEAD + h) * SEQ + q]);
  f32x4 a = *(const f32x4*)(A0 + i);
  f32x4 b = *(const f32x4*)(A1 + i);
#pragma unroll
  for (int j = 0; j < 4; j++) AO[i + j] = (__bf16)((a[j] + b[j]) * inv);
}

// ---------------------------------------------------------------------------

extern "C" void kernel_launch(void* const* d_in, const int* in_sizes, int n_in,
                              void* d_out, int out_size, void* d_ws, size_t ws_size,
                              hipStream_t stream) {
  const float* hidden = (const float*)d_in[0];
  const float* cosT   = (const float*)d_in[1];
  const float* sinT   = (const float*)d_in[2];
  // d_in[3] = mask (pure causal, computed analytically), d_in[4] = arange (unused)
  const float* WAq = (const float*)d_in[5];
  const float* WAk = (const float*)d_in[6];
  const float* WAv = (const float*)d_in[7];
  const float* WBq = (const float*)d_in[8];
  const float* WBk = (const float*)d_in[9];
  const float* WBv = (const float*)d_in[10];
  const float* Wo  = (const float*)d_in[11];
  float* out = (float*)d_out;

  // Workspace layout (lifetime-aliased), ~67.9 MB:
  //   [0)          hid_bf (8.39M)  -> AOf0 (16.78M) after proj is done
  //   [8388608)    WallT  (5.77M)      (overlaid by AOf0)
  //   [14155776)   Pp0    (11.53M)     (first 2.6M overlaid by AOf0; dead
  //                                     after build_qkv)
  //   [25690112)   WoT    (8.39M)      (live until final GEMM)
  //   [34078720)   Qb     (8.39M)  -> AO bf16 after attn is done
  //   [42467328)   Kb     (4.19M)
  //   [46661632)   Vt     (4.19M)
  //   [50855936)   Pp1    (11.53M) -> AOf1 (16.78M) after build_qkv is done
  //   [67633152)   Ls     (0.26M)
  char* ws = (char*)d_ws;
  __bf16* hid_bf = (__bf16*)(ws);
  __bf16* WallT  = (__bf16*)(ws + 8388608);
  float*  Pp0    = (float*)(ws + 14155776);
  __bf16* WoT    = (__bf16*)(ws + 25690112);
  __bf16* Qb     = (__bf16*)(ws + 34078720);
  __bf16* Kb     = (__bf16*)(ws + 42467328);
  __bf16* Vt     = (__bf16*)(ws + 46661632);
  float*  Pp1    = (float*)(ws + 50855936);
  float*  AOf0   = (float*)(ws);
  float*  AOf1   = (float*)(ws + 50855936);
  float*  Ls     = (float*)(ws + 67633152);
  __bf16* AO     = (__bf16*)(ws + 34078720);  // aliases Qb (dead after attn)

  // prep: 2048 cvt blocks + 44*64 wall-transpose
  k_prep<<<2048 + 44 * 64, 256, 0, stream>>>(
      hidden, WAq, WAk, WAv, WBq, WBk, WBv, hid_bf, WallT);
  // proj GEMM split-K=2 (704 blocks) + WoT transpose (4096 blocks) fused
  k_proj_wo<<<704 + 4096, 256, 0, stream>>>(hid_bf, WallT, Pp0, Pp1, Wo, WoT);
  k_build_qkv<<<SEQ, 128, 0, stream>>>(Pp0, Pp1, cosT, sinT, Qb, Kb, Vt);
  k_attn<<<1024, 256, 0, stream>>>(Qb, Kb, Vt, AOf0, AOf1, Ls);
  k_norm<<<(SEQ * HIDN / 4) / 256, 256, 0, stream>>>(AOf0, AOf1, Ls, AO);
  k_gemm_out<<<dim3(16, 16), 512, 0, stream>>>(AO, WoT, out);
}